// Round 2
// baseline (7089.934 us; speedup 1.0000x reference)
//
#include <hip/hip_runtime.h>
#include <hip/hip_bf16.h>

// ByteLevelDecoder: B=2,S=256,H=1024, BH=384,NH=8,HD=48, P=4,S_C=12,L=4,V=258,T=16
// Strategy: persistent kernel, 1 block = 2 sequences, whole forward per block.
// All f32 (inputs/outputs are f32 per reference). KV cache in d_ws.

constexpr int H_IN  = 1024;
constexpr int BH    = 384;
constexpr int NH    = 8;
constexpr int HD    = 48;
constexpr int PP    = 4;
constexpr int S_CNT = 12;
constexpr int NL    = 4;
constexpr int NV    = 258;
constexpr int TT    = 16;
constexpr int NSEQ  = 512;
constexpr int EOS_I = 257;
constexpr int NTH   = 384;
constexpr float RSCALE = 0.14433756729740646f;  // 1/sqrt(48)

template<int N> struct IC { static constexpr int value = N; };

__global__ __launch_bounds__(NTH)
void decoder_kernel(const float* __restrict__ x,
                    const float* __restrict__ Wproj,
                    const float* __restrict__ attn_norm,
                    const float* __restrict__ Wq,
                    const float* __restrict__ Wk,
                    const float* __restrict__ Wv,
                    const float* __restrict__ Wo,
                    const float* __restrict__ ffn_norm,
                    const float* __restrict__ W1,
                    const float* __restrict__ W2,
                    const float* __restrict__ Wlm,
                    float* __restrict__ out,
                    float* __restrict__ kbuf, float* __restrict__ vbuf)
{
  __shared__ float xs[2][4][BH];   // residual stream (up to 4 prefill tokens)
  __shared__ float hs[2][4][BH];   // rms-normed
  __shared__ float qs[2][4][BH];
  __shared__ float os[2][4][BH];   // attention out
  __shared__ float f1[2][4*BH];    // FFN intermediate; also reused to stage x row
  __shared__ float sc[2][NH][4][TT];
  __shared__ float redsum[8];
  __shared__ float redv[8];
  __shared__ int   redi[8];
  __shared__ int   amx[2];
  __shared__ int   fin[2];

  const int tid  = threadIdx.x;
  const int seq0 = blockIdx.x * 2;

  auto block_sum = [&](float v) -> float {
    #pragma unroll
    for (int off = 32; off; off >>= 1) v += __shfl_down(v, off, 64);
    if ((tid & 63) == 0) redsum[tid >> 6] = v;
    __syncthreads();
    float s = redsum[0] + redsum[1] + redsum[2] + redsum[3] + redsum[4] + redsum[5];
    __syncthreads();
    return s;
  };

  if (tid < 2) fin[tid] = 0;

  // ---- x0 = (x_row @ Wproj).reshape(P, BH) ----
  for (int s = 0; s < 2; s++) {
    const size_t base = (size_t)(seq0 + s) * H_IN;
    for (int j = tid; j < H_IN; j += NTH) f1[s][j] = x[base + j];
  }
  __syncthreads();
  {
    float acc[2][4] = {};
    for (int j = 0; j < H_IN; j++) {
      float x0 = f1[0][j], x1 = f1[1][j];
      #pragma unroll
      for (int m = 0; m < 4; m++) {
        float w = Wproj[(size_t)j * (PP * BH) + m * BH + tid];
        acc[0][m] += x0 * w; acc[1][m] += x1 * w;
      }
    }
    __syncthreads();
    for (int s = 0; s < 2; s++)
      #pragma unroll
      for (int m = 0; m < 4; m++) xs[s][m][tid] = acc[s][m];
  }
  __syncthreads();

  auto layers = [&](auto ntc, int pos, bool causal) {
    constexpr int NT = decltype(ntc)::value;
    const int nk = pos + NT;
    for (int l = 0; l < NL; l++) {
      // ---- attn RMSNorm ----
      for (int s = 0; s < 2; s++)
        for (int tok = 0; tok < NT; tok++) {
          float v  = xs[s][tok][tid];
          float ss = block_sum(v * v);
          float sca = rsqrtf(ss * (1.0f / BH) + 1e-5f);
          hs[s][tok][tid] = v * sca * attn_norm[l * BH + tid];
        }
      __syncthreads();
      // ---- q,k,v = h @ Wq/Wk/Wv ; write k,v to cache ----
      {
        const float* wq = Wq + (size_t)l * BH * BH;
        const float* wk = Wk + (size_t)l * BH * BH;
        const float* wv = Wv + (size_t)l * BH * BH;
        float aq[2][NT] = {}, ak[2][NT] = {}, av[2][NT] = {};
        for (int j = 0; j < BH; j++) {
          float wqv = wq[j * BH + tid];
          float wkv = wk[j * BH + tid];
          float wvv = wv[j * BH + tid];
          #pragma unroll
          for (int s = 0; s < 2; s++)
            #pragma unroll
            for (int tok = 0; tok < NT; tok++) {
              float hv = hs[s][tok][j];
              aq[s][tok] += hv * wqv; ak[s][tok] += hv * wkv; av[s][tok] += hv * wvv;
            }
        }
        for (int s = 0; s < 2; s++) {
          const size_t cb = (((size_t)(seq0 + s) * NL + l) * TT + pos) * BH + tid;
          #pragma unroll
          for (int tok = 0; tok < NT; tok++) {
            qs[s][tok][tid] = aq[s][tok];
            kbuf[cb + (size_t)tok * BH] = ak[s][tok];
            vbuf[cb + (size_t)tok * BH] = av[s][tok];
          }
        }
      }
      __syncthreads();
      // ---- scores ----
      {
        const int nu = 2 * NH * NT * nk;
        if (tid < nu) {
          int s = tid / (NH * NT * nk), r = tid % (NH * NT * nk);
          int h = r / (NT * nk); int r2 = r % (NT * nk);
          int qi = r2 / nk, j = r2 % nk;
          float d;
          if (causal && j > pos + qi) d = -1e30f;
          else {
            d = 0.f;
            const size_t kb = (((size_t)(seq0 + s) * NL + l) * TT + j) * BH + h * HD;
            #pragma unroll
            for (int dd = 0; dd < HD; dd++)
              d += qs[s][qi][h * HD + dd] * kbuf[kb + dd];
            d *= RSCALE;
          }
          sc[s][h][qi][j] = d;
        }
      }
      __syncthreads();
      // ---- softmax over keys ----
      {
        const int nr = 2 * NH * NT;
        if (tid < nr) {
          int s = tid / (NH * NT), r = tid % (NH * NT);
          int h = r / NT, qi = r % NT;
          float m = -3.0e38f;
          for (int j = 0; j < nk; j++) m = fmaxf(m, sc[s][h][qi][j]);
          float den = 0.f;
          for (int j = 0; j < nk; j++) {
            float e = expf(sc[s][h][qi][j] - m);
            sc[s][h][qi][j] = e; den += e;
          }
          float inv = 1.0f / den;
          for (int j = 0; j < nk; j++) sc[s][h][qi][j] *= inv;
        }
      }
      __syncthreads();
      // ---- o = p @ V ----
      for (int s = 0; s < 2; s++) {
        const size_t vb = (((size_t)(seq0 + s) * NL + l) * TT) * BH + tid;
        const int h = tid / HD;
        #pragma unroll
        for (int tok = 0; tok < NT; tok++) {
          float acc = 0.f;
          for (int j = 0; j < nk; j++)
            acc += sc[s][h][tok][j] * vbuf[vb + (size_t)j * BH];
          os[s][tok][tid] = acc;
        }
      }
      __syncthreads();
      // ---- x += o @ Wo ----
      {
        const float* wo = Wo + (size_t)l * BH * BH;
        float ao[2][NT] = {};
        for (int j = 0; j < BH; j++) {
          float wv_ = wo[j * BH + tid];
          #pragma unroll
          for (int s = 0; s < 2; s++)
            #pragma unroll
            for (int tok = 0; tok < NT; tok++) ao[s][tok] += os[s][tok][j] * wv_;
        }
        #pragma unroll
        for (int s = 0; s < 2; s++)
          #pragma unroll
          for (int tok = 0; tok < NT; tok++) xs[s][tok][tid] += ao[s][tok];
      }
      __syncthreads();
      // ---- ffn RMSNorm ----
      for (int s = 0; s < 2; s++)
        for (int tok = 0; tok < NT; tok++) {
          float v  = xs[s][tok][tid];
          float ss = block_sum(v * v);
          float sca = rsqrtf(ss * (1.0f / BH) + 1e-5f);
          hs[s][tok][tid] = v * sca * ffn_norm[l * BH + tid];
        }
      __syncthreads();
      // ---- x += gelu(h2 @ W1) @ W2 (per token to bound LDS) ----
      {
        const float* w1 = W1 + (size_t)l * BH * (4 * BH);
        const float* w2 = W2 + (size_t)l * (4 * BH) * BH;
        for (int tok = 0; tok < NT; tok++) {
          float a1[2][4] = {};
          for (int j = 0; j < BH; j++) {
            float h0 = hs[0][tok][j], h1 = hs[1][tok][j];
            #pragma unroll
            for (int m = 0; m < 4; m++) {
              float wv_ = w1[(size_t)j * (4 * BH) + m * BH + tid];
              a1[0][m] += h0 * wv_; a1[1][m] += h1 * wv_;
            }
          }
          #pragma unroll
          for (int s = 0; s < 2; s++)
            #pragma unroll
            for (int m = 0; m < 4; m++) {
              float z = a1[s][m];
              f1[s][m * BH + tid] = 0.5f * z * (1.0f + erff(z * 0.7071067811865476f));
            }
          __syncthreads();
          float a2[2] = {};
          for (int j = 0; j < 4 * BH; j++) {
            float wv_ = w2[(size_t)j * BH + tid];
            a2[0] += f1[0][j] * wv_; a2[1] += f1[1][j] * wv_;
          }
          xs[0][tok][tid] += a2[0];
          xs[1][tok][tid] += a2[1];
          __syncthreads();
        }
      }
    }
  };

  for (int i = 0; i < S_CNT; i++) {
    int grow;
    if (i == 0) { layers(IC<4>{}, 0, true);           grow = 3; }
    else        { layers(IC<1>{}, PP + i - 1, false); grow = 0; }

    // ---- argmax over hidden dims (first-max tie-break like jnp.argmax) ----
    for (int s = 0; s < 2; s++) {
      float v = xs[s][grow][tid]; int idx = tid;
      #pragma unroll
      for (int off = 32; off; off >>= 1) {
        float v2 = __shfl_down(v, off, 64); int i2 = __shfl_down(idx, off, 64);
        if (v2 > v || (v2 == v && i2 < idx)) { v = v2; idx = i2; }
      }
      if ((tid & 63) == 0) { redv[tid >> 6] = v; redi[tid >> 6] = idx; }
      __syncthreads();
      if (tid == 0) {
        float bv = redv[0]; int bi = redi[0];
        for (int w = 1; w < 6; w++)
          if (redv[w] > bv || (redv[w] == bv && redi[w] < bi)) { bv = redv[w]; bi = redi[w]; }
        amx[s] = bi;
      }
      __syncthreads();
    }
    // ---- logits for this step (zeroed if already finished) ----
    for (int s = 0; s < 2; s++) {
      if (tid < NV) {
        float acc = 0.f;
        for (int j = 0; j < BH; j++) acc += xs[s][grow][j] * Wlm[(size_t)j * NV + tid];
        float val = fin[s] ? 0.0f : acc;
        out[((size_t)(seq0 + s) * S_CNT + i) * NV + tid] = val;
      }
    }
    __syncthreads();
    // ---- next token = (finished ? 0 : gen); then update finished ----
    for (int s = 0; s < 2; s++) {
      float gv = xs[s][grow][tid];
      xs[s][0][tid] = fin[s] ? 0.0f : gv;
    }
    __syncthreads();
    if (tid < 2 && amx[tid] == EOS_I) fin[tid] = 1;
    __syncthreads();
  }
}

extern "C" void kernel_launch(void* const* d_in, const int* in_sizes, int n_in,
                              void* d_out, int out_size, void* d_ws, size_t ws_size,
                              hipStream_t stream) {
  const float* x     = (const float*)d_in[0];
  // d_in[1] = target (unused)
  const float* Wproj = (const float*)d_in[2];
  const float* an    = (const float*)d_in[3];
  const float* Wq    = (const float*)d_in[4];
  const float* Wk    = (const float*)d_in[5];
  const float* Wv    = (const float*)d_in[6];
  const float* Wo    = (const float*)d_in[7];
  const float* fn    = (const float*)d_in[8];
  const float* W1    = (const float*)d_in[9];
  const float* W2    = (const float*)d_in[10];
  const float* Wlm   = (const float*)d_in[11];
  float* out = (float*)d_out;

  const size_t kv_elems = (size_t)NSEQ * NL * TT * BH;   // per k or v
  float* kbuf = (float*)d_ws;
  float* vbuf = kbuf + kv_elems;
  (void)ws_size; (void)in_sizes; (void)n_in; (void)out_size;

  decoder_kernel<<<NSEQ / 2, NTH, 0, stream>>>(
      x, Wproj, an, Wq, Wk, Wv, Wo, fn, W1, W2, Wlm, out, kbuf, vbuf);
}

// Round 3
// 6833.416 us; speedup vs baseline: 1.0375x; 1.0375x over previous
//
#include <hip/hip_runtime.h>
#include <hip/hip_bf16.h>

// ByteLevelDecoder: B=2,S=256,H=1024, BH=384,NH=8,HD=48, P=4,S_C=12,L=4,V=258,T=16
// Persistent kernel, 1 block = 2 sequences. Activations/accum f32 in LDS.
// Weights converted f32->bf16 into d_ws by a prepass (halves L2/LLC streaming
// traffic: 87 GB -> 43.5 GB; per-layer set 3.5 MB < 4 MB XCD-L2 enables reuse).
// KV cache bf16 in d_ws.

constexpr int H_IN  = 1024;
constexpr int BH    = 384;
constexpr int NH    = 8;
constexpr int HD    = 48;
constexpr int PP    = 4;
constexpr int S_CNT = 12;
constexpr int NL    = 4;
constexpr int NV    = 258;
constexpr int TT    = 16;
constexpr int NSEQ  = 512;
constexpr int EOS_I = 257;
constexpr int NTH   = 384;
constexpr float RSCALE = 0.14433756729740646f;  // 1/sqrt(48)

template<int N> struct IC { static constexpr int value = N; };

__device__ __forceinline__ float b2f(const __hip_bfloat16 h) { return __bfloat162float(h); }

// ---- f32 -> bf16 conversion prepass (4 elems/thread, n % 4 == 0) ----
__global__ __launch_bounds__(256)
void cvt_kernel(const float* __restrict__ src, __hip_bfloat16* __restrict__ dst, int n) {
  int i4 = (blockIdx.x * 256 + threadIdx.x) * 4;
  if (i4 < n) {
    float4 v = *(const float4*)(src + i4);
    dst[i4 + 0] = __float2bfloat16(v.x);
    dst[i4 + 1] = __float2bfloat16(v.y);
    dst[i4 + 2] = __float2bfloat16(v.z);
    dst[i4 + 3] = __float2bfloat16(v.w);
  }
}

__global__ __launch_bounds__(NTH)
void decoder_kernel(const float* __restrict__ x,
                    const __hip_bfloat16* __restrict__ Wproj,
                    const float* __restrict__ attn_norm,
                    const __hip_bfloat16* __restrict__ Wq,
                    const __hip_bfloat16* __restrict__ Wk,
                    const __hip_bfloat16* __restrict__ Wv,
                    const __hip_bfloat16* __restrict__ Wo,
                    const float* __restrict__ ffn_norm,
                    const __hip_bfloat16* __restrict__ W1,
                    const __hip_bfloat16* __restrict__ W2,
                    const __hip_bfloat16* __restrict__ Wlm,
                    float* __restrict__ out,
                    __hip_bfloat16* __restrict__ kbuf,
                    __hip_bfloat16* __restrict__ vbuf)
{
  __shared__ float xs[2][4][BH];   // residual stream (up to 4 prefill tokens)
  __shared__ float hs[2][4][BH];   // rms-normed
  __shared__ float qs[2][4][BH];
  __shared__ float os[2][4][BH];   // attention out
  __shared__ float f1[2][4*BH];    // FFN intermediate; also reused to stage x row
  __shared__ float sc[2][NH][4][TT];
  __shared__ float redsum[8];
  __shared__ float redv[8];
  __shared__ int   redi[8];
  __shared__ int   amx[2];
  __shared__ int   fin[2];

  const int tid  = threadIdx.x;
  const int seq0 = blockIdx.x * 2;

  auto block_sum = [&](float v) -> float {
    #pragma unroll
    for (int off = 32; off; off >>= 1) v += __shfl_down(v, off, 64);
    if ((tid & 63) == 0) redsum[tid >> 6] = v;
    __syncthreads();
    float s = redsum[0] + redsum[1] + redsum[2] + redsum[3] + redsum[4] + redsum[5];
    __syncthreads();
    return s;
  };

  if (tid < 2) fin[tid] = 0;

  // ---- x0 = (x_row @ Wproj).reshape(P, BH) ----
  for (int s = 0; s < 2; s++) {
    const size_t base = (size_t)(seq0 + s) * H_IN;
    for (int j = tid; j < H_IN; j += NTH) f1[s][j] = x[base + j];
  }
  __syncthreads();
  {
    float acc[2][4] = {};
    for (int j = 0; j < H_IN; j++) {
      float x0 = f1[0][j], x1 = f1[1][j];
      #pragma unroll
      for (int m = 0; m < 4; m++) {
        float w = b2f(Wproj[(size_t)j * (PP * BH) + m * BH + tid]);
        acc[0][m] += x0 * w; acc[1][m] += x1 * w;
      }
    }
    __syncthreads();
    for (int s = 0; s < 2; s++)
      #pragma unroll
      for (int m = 0; m < 4; m++) xs[s][m][tid] = acc[s][m];
  }
  __syncthreads();

  auto layers = [&](auto ntc, int pos, bool causal) {
    constexpr int NT = decltype(ntc)::value;
    const int nk = pos + NT;
    for (int l = 0; l < NL; l++) {
      // ---- attn RMSNorm ----
      for (int s = 0; s < 2; s++)
        for (int tok = 0; tok < NT; tok++) {
          float v  = xs[s][tok][tid];
          float ss = block_sum(v * v);
          float sca = rsqrtf(ss * (1.0f / BH) + 1e-5f);
          hs[s][tok][tid] = v * sca * attn_norm[l * BH + tid];
        }
      __syncthreads();
      // ---- q,k,v = h @ Wq/Wk/Wv ; write k,v to cache ----
      {
        const __hip_bfloat16* wq = Wq + (size_t)l * BH * BH;
        const __hip_bfloat16* wk = Wk + (size_t)l * BH * BH;
        const __hip_bfloat16* wv = Wv + (size_t)l * BH * BH;
        float aq[2][NT] = {}, ak[2][NT] = {}, av[2][NT] = {};
        for (int j = 0; j < BH; j++) {
          float wqv = b2f(wq[j * BH + tid]);
          float wkv = b2f(wk[j * BH + tid]);
          float wvv = b2f(wv[j * BH + tid]);
          #pragma unroll
          for (int s = 0; s < 2; s++)
            #pragma unroll
            for (int tok = 0; tok < NT; tok++) {
              float hv = hs[s][tok][j];
              aq[s][tok] += hv * wqv; ak[s][tok] += hv * wkv; av[s][tok] += hv * wvv;
            }
        }
        for (int s = 0; s < 2; s++) {
          const size_t cb = (((size_t)(seq0 + s) * NL + l) * TT + pos) * BH + tid;
          #pragma unroll
          for (int tok = 0; tok < NT; tok++) {
            qs[s][tok][tid] = aq[s][tok];
            kbuf[cb + (size_t)tok * BH] = __float2bfloat16(ak[s][tok]);
            vbuf[cb + (size_t)tok * BH] = __float2bfloat16(av[s][tok]);
          }
        }
      }
      __syncthreads();
      // ---- scores ----
      {
        const int nu = 2 * NH * NT * nk;
        if (tid < nu) {
          int s = tid / (NH * NT * nk), r = tid % (NH * NT * nk);
          int h = r / (NT * nk); int r2 = r % (NT * nk);
          int qi = r2 / nk, j = r2 % nk;
          float d;
          if (causal && j > pos + qi) d = -1e30f;
          else {
            d = 0.f;
            const size_t kb = (((size_t)(seq0 + s) * NL + l) * TT + j) * BH + h * HD;
            #pragma unroll
            for (int dd = 0; dd < HD; dd++)
              d += qs[s][qi][h * HD + dd] * b2f(kbuf[kb + dd]);
            d *= RSCALE;
          }
          sc[s][h][qi][j] = d;
        }
      }
      __syncthreads();
      // ---- softmax over keys ----
      {
        const int nr = 2 * NH * NT;
        if (tid < nr) {
          int s = tid / (NH * NT), r = tid % (NH * NT);
          int h = r / NT, qi = r % NT;
          float m = -3.0e38f;
          for (int j = 0; j < nk; j++) m = fmaxf(m, sc[s][h][qi][j]);
          float den = 0.f;
          for (int j = 0; j < nk; j++) {
            float e = expf(sc[s][h][qi][j] - m);
            sc[s][h][qi][j] = e; den += e;
          }
          float inv = 1.0f / den;
          for (int j = 0; j < nk; j++) sc[s][h][qi][j] *= inv;
        }
      }
      __syncthreads();
      // ---- o = p @ V ----
      for (int s = 0; s < 2; s++) {
        const size_t vb = (((size_t)(seq0 + s) * NL + l) * TT) * BH + tid;
        const int h = tid / HD;
        #pragma unroll
        for (int tok = 0; tok < NT; tok++) {
          float acc = 0.f;
          for (int j = 0; j < nk; j++)
            acc += sc[s][h][tok][j] * b2f(vbuf[vb + (size_t)j * BH]);
          os[s][tok][tid] = acc;
        }
      }
      __syncthreads();
      // ---- x += o @ Wo ----
      {
        const __hip_bfloat16* wo = Wo + (size_t)l * BH * BH;
        float ao[2][NT] = {};
        for (int j = 0; j < BH; j++) {
          float wv_ = b2f(wo[j * BH + tid]);
          #pragma unroll
          for (int s = 0; s < 2; s++)
            #pragma unroll
            for (int tok = 0; tok < NT; tok++) ao[s][tok] += os[s][tok][j] * wv_;
        }
        #pragma unroll
        for (int s = 0; s < 2; s++)
          #pragma unroll
          for (int tok = 0; tok < NT; tok++) xs[s][tok][tid] += ao[s][tok];
      }
      __syncthreads();
      // ---- ffn RMSNorm ----
      for (int s = 0; s < 2; s++)
        for (int tok = 0; tok < NT; tok++) {
          float v  = xs[s][tok][tid];
          float ss = block_sum(v * v);
          float sca = rsqrtf(ss * (1.0f / BH) + 1e-5f);
          hs[s][tok][tid] = v * sca * ffn_norm[l * BH + tid];
        }
      __syncthreads();
      // ---- x += gelu(h2 @ W1) @ W2 (per token to bound LDS) ----
      {
        const __hip_bfloat16* w1 = W1 + (size_t)l * BH * (4 * BH);
        const __hip_bfloat16* w2 = W2 + (size_t)l * (4 * BH) * BH;
        for (int tok = 0; tok < NT; tok++) {
          float a1[2][4] = {};
          for (int j = 0; j < BH; j++) {
            float h0 = hs[0][tok][j], h1 = hs[1][tok][j];
            #pragma unroll
            for (int m = 0; m < 4; m++) {
              float wv_ = b2f(w1[(size_t)j * (4 * BH) + m * BH + tid]);
              a1[0][m] += h0 * wv_; a1[1][m] += h1 * wv_;
            }
          }
          #pragma unroll
          for (int s = 0; s < 2; s++)
            #pragma unroll
            for (int m = 0; m < 4; m++) {
              float z = a1[s][m];
              f1[s][m * BH + tid] = 0.5f * z * (1.0f + erff(z * 0.7071067811865476f));
            }
          __syncthreads();
          float a2[2] = {};
          for (int j = 0; j < 4 * BH; j++) {
            float wv_ = b2f(w2[(size_t)j * BH + tid]);
            a2[0] += f1[0][j] * wv_; a2[1] += f1[1][j] * wv_;
          }
          xs[0][tok][tid] += a2[0];
          xs[1][tok][tid] += a2[1];
          __syncthreads();
        }
      }
    }
  };

  for (int i = 0; i < S_CNT; i++) {
    int grow;
    if (i == 0) { layers(IC<4>{}, 0, true);           grow = 3; }
    else        { layers(IC<1>{}, PP + i - 1, false); grow = 0; }

    // ---- argmax over hidden dims (first-max tie-break like jnp.argmax) ----
    for (int s = 0; s < 2; s++) {
      float v = xs[s][grow][tid]; int idx = tid;
      #pragma unroll
      for (int off = 32; off; off >>= 1) {
        float v2 = __shfl_down(v, off, 64); int i2 = __shfl_down(idx, off, 64);
        if (v2 > v || (v2 == v && i2 < idx)) { v = v2; idx = i2; }
      }
      if ((tid & 63) == 0) { redv[tid >> 6] = v; redi[tid >> 6] = idx; }
      __syncthreads();
      if (tid == 0) {
        float bv = redv[0]; int bi = redi[0];
        for (int w = 1; w < 6; w++)
          if (redv[w] > bv || (redv[w] == bv && redi[w] < bi)) { bv = redv[w]; bi = redi[w]; }
        amx[s] = bi;
      }
      __syncthreads();
    }
    // ---- logits for this step (zeroed if already finished) ----
    for (int s = 0; s < 2; s++) {
      if (tid < NV) {
        float acc = 0.f;
        for (int j = 0; j < BH; j++) acc += xs[s][grow][j] * b2f(Wlm[(size_t)j * NV + tid]);
        float val = fin[s] ? 0.0f : acc;
        out[((size_t)(seq0 + s) * S_CNT + i) * NV + tid] = val;
      }
    }
    __syncthreads();
    // ---- next token = (finished ? 0 : gen); then update finished ----
    for (int s = 0; s < 2; s++) {
      float gv = xs[s][grow][tid];
      xs[s][0][tid] = fin[s] ? 0.0f : gv;
    }
    __syncthreads();
    if (tid < 2 && amx[tid] == EOS_I) fin[tid] = 1;
    __syncthreads();
  }
}

extern "C" void kernel_launch(void* const* d_in, const int* in_sizes, int n_in,
                              void* d_out, int out_size, void* d_ws, size_t ws_size,
                              hipStream_t stream) {
  const float* x     = (const float*)d_in[0];
  // d_in[1] = target (unused)
  const float* Wproj = (const float*)d_in[2];
  const float* an    = (const float*)d_in[3];
  const float* Wq    = (const float*)d_in[4];
  const float* Wk    = (const float*)d_in[5];
  const float* Wv    = (const float*)d_in[6];
  const float* Wo    = (const float*)d_in[7];
  const float* fn    = (const float*)d_in[8];
  const float* W1    = (const float*)d_in[9];
  const float* W2    = (const float*)d_in[10];
  const float* Wlm   = (const float*)d_in[11];
  float* out = (float*)d_out;
  (void)ws_size; (void)in_sizes; (void)n_in; (void)out_size;

  // ---- carve d_ws: bf16 weights, then bf16 KV ----
  __hip_bfloat16* w = (__hip_bfloat16*)d_ws;
  const int n_proj = H_IN * PP * BH;        // 1,572,864
  const int n_qkvo = NL * BH * BH;          //   589,824 each
  const int n_ffn  = NL * BH * 4 * BH;      // 2,359,296 each
  const int n_lm   = BH * NV;               //    99,072
  __hip_bfloat16* Wproj_b = w;              w += n_proj;
  __hip_bfloat16* Wq_b    = w;              w += n_qkvo;
  __hip_bfloat16* Wk_b    = w;              w += n_qkvo;
  __hip_bfloat16* Wv_b    = w;              w += n_qkvo;
  __hip_bfloat16* Wo_b    = w;              w += n_qkvo;
  __hip_bfloat16* W1_b    = w;              w += n_ffn;
  __hip_bfloat16* W2_b    = w;              w += n_ffn;
  __hip_bfloat16* Wlm_b   = w;              w += n_lm;
  const size_t kv_elems = (size_t)NSEQ * NL * TT * BH;  // 12,582,912
  __hip_bfloat16* kbuf = w;                 w += kv_elems;
  __hip_bfloat16* vbuf = w;

  auto cvt = [&](const float* src, __hip_bfloat16* dst, int n) {
    int blocks = (n / 4 + 255) / 256;
    cvt_kernel<<<blocks, 256, 0, stream>>>(src, dst, n);
  };
  cvt(Wproj, Wproj_b, n_proj);
  cvt(Wq,    Wq_b,    n_qkvo);
  cvt(Wk,    Wk_b,    n_qkvo);
  cvt(Wv,    Wv_b,    n_qkvo);
  cvt(Wo,    Wo_b,    n_qkvo);
  cvt(W1,    W1_b,    n_ffn);
  cvt(W2,    W2_b,    n_ffn);
  cvt(Wlm,   Wlm_b,   n_lm);

  decoder_kernel<<<NSEQ / 2, NTH, 0, stream>>>(
      x, Wproj_b, an, Wq_b, Wk_b, Wv_b, Wo_b, fn, W1_b, W2_b, Wlm_b, out, kbuf, vbuf);
}

// Round 4
// 6476.328 us; speedup vs baseline: 1.0947x; 1.0551x over previous
//
#include <hip/hip_runtime.h>
#include <hip/hip_bf16.h>

// ByteLevelDecoder: B=2,S=256,H=1024, BH=384,NH=8,HD=48, P=4,S_C=12,L=4,V=258,T=16
// Persistent kernel, 1 block = 2 sequences, 768 threads (group g of 384 owns seq g).
// Weights repacked f32 -> half2 (pairs along reduction dim) in d_ws by a prepass;
// inner loops use v_dot2_f32_f16 (1 dword load + 1 dot2 per 2 weights).
// Activations f32 in LDS, packed to half2 on the fly. KV cache f16 in d_ws.

constexpr int H_IN  = 1024;
constexpr int BH    = 384;
constexpr int NH    = 8;
constexpr int HD    = 48;
constexpr int PP    = 4;
constexpr int S_CNT = 12;
constexpr int NL    = 4;
constexpr int NV    = 258;
constexpr int TT    = 16;
constexpr int NSEQ  = 512;
constexpr int EOS_I = 257;
constexpr int NTH   = 768;     // 2 groups x 384
constexpr int GSZ   = 384;
constexpr float RSCALE = 0.14433756729740646f;  // 1/sqrt(48)

typedef _Float16 h2 __attribute__((ext_vector_type(2)));

template<int N> struct IC { static constexpr int value = N; };

__device__ __forceinline__ float fdot2(h2 a, h2 b, float c) {
#if __has_builtin(__builtin_amdgcn_fdot2)
  return __builtin_amdgcn_fdot2(a, b, c, false);
#else
  return c + (float)a.x * (float)b.x + (float)a.y * (float)b.y;
#endif
}

__device__ __forceinline__ h2 pack2(float a, float b) {
  h2 r; r.x = (_Float16)a; r.y = (_Float16)b; return r;
}

// ---- repack prepass: dst[j2*C + c] = (src[2*j2][c], src[2*j2+1][c]) ----
__global__ __launch_bounds__(256)
void pack_kernel(const float* __restrict__ src, h2* __restrict__ dst, int C) {
  int c  = blockIdx.x * 256 + threadIdx.x;
  int j2 = blockIdx.y;
  if (c < C) {
    dst[(size_t)j2 * C + c] =
        pack2(src[(size_t)(2 * j2) * C + c], src[(size_t)(2 * j2 + 1) * C + c]);
  }
}

__global__ __launch_bounds__(NTH)
void decoder_kernel(const float* __restrict__ x,
                    const h2* __restrict__ Wproj,     // [512][1536]
                    const float* __restrict__ attn_norm,
                    const h2* __restrict__ Wq,        // [l][192][384]
                    const h2* __restrict__ Wk,
                    const h2* __restrict__ Wv,
                    const h2* __restrict__ Wo,
                    const float* __restrict__ ffn_norm,
                    const h2* __restrict__ W1,        // [l][192][1536]
                    const h2* __restrict__ W2,        // [l][768][384]
                    const h2* __restrict__ Wlm,       // [192][258]
                    float* __restrict__ out,
                    _Float16* __restrict__ kbuf,
                    _Float16* __restrict__ vbuf)
{
  __shared__ float xs[2][4][BH];     // residual stream
  __shared__ h2    hpk[2][4][BH/2];  // packed normed activations / packed os / gen row
  __shared__ float qs[2][4][BH];
  __shared__ float os[2][4][BH];
  __shared__ float f1[2][4*BH];      // f32 gelu out (current tok)
  __shared__ h2    f1pk[2][2*BH];    // packed gelu out (768 pairs)
  __shared__ h2    xpk[2][H_IN/2];   // packed input x
  __shared__ float sc[2][NH][4][TT];
  __shared__ float redsum[12];
  __shared__ float redv[12];
  __shared__ int   redi[12];
  __shared__ int   amx[2];
  __shared__ int   fin[2];

  const int tid  = threadIdx.x;
  const int g    = tid / GSZ;        // group = sequence within block
  const int col  = tid - g * GSZ;    // 0..383
  const int seq0 = blockIdx.x * 2;
  const int seq  = seq0 + g;

  auto group_sum = [&](float v) -> float {
    #pragma unroll
    for (int off = 32; off; off >>= 1) v += __shfl_down(v, off, 64);
    if ((tid & 63) == 0) redsum[tid >> 6] = v;
    __syncthreads();
    const int base = g * 6;
    float s = redsum[base] + redsum[base+1] + redsum[base+2] +
              redsum[base+3] + redsum[base+4] + redsum[base+5];
    __syncthreads();
    return s;
  };

  if (tid < 2) fin[tid] = 0;

  // ---- stage packed x, then x0 = (x_row @ Wproj).reshape(P, BH) ----
  {
    const size_t base = (size_t)seq * H_IN;
    for (int j2 = col; j2 < H_IN/2; j2 += GSZ)
      xpk[g][j2] = pack2(x[base + 2*j2], x[base + 2*j2 + 1]);
  }
  __syncthreads();
  {
    float acc[4] = {};
    for (int j2 = 0; j2 < H_IN/2; j2++) {
      h2 xv = xpk[g][j2];
      #pragma unroll
      for (int m = 0; m < 4; m++)
        acc[m] = fdot2(xv, Wproj[(size_t)j2 * (PP*BH) + m*BH + col], acc[m]);
    }
    #pragma unroll
    for (int m = 0; m < 4; m++) xs[g][m][col] = acc[m];
  }
  __syncthreads();

  auto layers = [&](auto ntc, int pos, bool causal) {
    constexpr int NT = decltype(ntc)::value;
    const int nk = pos + NT;
    for (int l = 0; l < NL; l++) {
      // ---- attn RMSNorm -> packed hpk ----
      for (int tok = 0; tok < NT; tok++) {
        float v  = xs[g][tok][col];
        float ss = group_sum(v * v);
        float sca = rsqrtf(ss * (1.0f / BH) + 1e-5f);
        if (col < BH/2) {
          float a = xs[g][tok][2*col]   * sca * attn_norm[l*BH + 2*col];
          float b = xs[g][tok][2*col+1] * sca * attn_norm[l*BH + 2*col+1];
          hpk[g][tok][col] = pack2(a, b);
        }
      }
      __syncthreads();
      // ---- q,k,v = h @ Wq/Wk/Wv ; write k,v to cache ----
      {
        const h2* wq = Wq + (size_t)l * (BH/2) * BH;
        const h2* wk = Wk + (size_t)l * (BH/2) * BH;
        const h2* wv = Wv + (size_t)l * (BH/2) * BH;
        float aq[NT] = {}, ak[NT] = {}, av[NT] = {};
        #pragma unroll 4
        for (int j2 = 0; j2 < BH/2; j2++) {
          h2 wqv = wq[j2*BH + col];
          h2 wkv = wk[j2*BH + col];
          h2 wvv = wv[j2*BH + col];
          #pragma unroll
          for (int tok = 0; tok < NT; tok++) {
            h2 hv = hpk[g][tok][j2];
            aq[tok] = fdot2(hv, wqv, aq[tok]);
            ak[tok] = fdot2(hv, wkv, ak[tok]);
            av[tok] = fdot2(hv, wvv, av[tok]);
          }
        }
        const size_t cb = (((size_t)seq * NL + l) * TT + pos) * BH + col;
        #pragma unroll
        for (int tok = 0; tok < NT; tok++) {
          qs[g][tok][col] = aq[tok];
          kbuf[cb + (size_t)tok * BH] = (_Float16)ak[tok];
          vbuf[cb + (size_t)tok * BH] = (_Float16)av[tok];
        }
      }
      __syncthreads();
      // ---- scores (256 lanes cover all) ----
      {
        const int nu = 2 * NH * NT * nk;
        if (tid < nu) {
          int s = tid / (NH * NT * nk), r = tid % (NH * NT * nk);
          int h = r / (NT * nk); int r2 = r % (NT * nk);
          int qi = r2 / nk, j = r2 % nk;
          float d;
          if (causal && j > pos + qi) d = -1e30f;
          else {
            d = 0.f;
            const size_t kb = (((size_t)(seq0 + s) * NL + l) * TT + j) * BH + h * HD;
            #pragma unroll
            for (int dd = 0; dd < HD; dd++)
              d += qs[s][qi][h*HD + dd] * (float)kbuf[kb + dd];
            d *= RSCALE;
          }
          sc[s][h][qi][j] = d;
        }
      }
      __syncthreads();
      // ---- softmax over keys ----
      {
        const int nr = 2 * NH * NT;
        if (tid < nr) {
          int s = tid / (NH * NT), r = tid % (NH * NT);
          int h = r / NT, qi = r % NT;
          float m = -3.0e38f;
          for (int j = 0; j < nk; j++) m = fmaxf(m, sc[s][h][qi][j]);
          float den = 0.f;
          for (int j = 0; j < nk; j++) {
            float e = expf(sc[s][h][qi][j] - m);
            sc[s][h][qi][j] = e; den += e;
          }
          float inv = 1.0f / den;
          for (int j = 0; j < nk; j++) sc[s][h][qi][j] *= inv;
        }
      }
      __syncthreads();
      // ---- o = p @ V ----
      {
        const size_t vb = (((size_t)seq * NL + l) * TT) * BH + col;
        const int h = col / HD;
        #pragma unroll
        for (int tok = 0; tok < NT; tok++) {
          float acc = 0.f;
          for (int j = 0; j < nk; j++)
            acc += sc[g][h][tok][j] * (float)vbuf[vb + (size_t)j * BH];
          os[g][tok][col] = acc;
        }
      }
      __syncthreads();
      // ---- pack os -> hpk ----
      if (col < BH/2) {
        #pragma unroll
        for (int tok = 0; tok < NT; tok++)
          hpk[g][tok][col] = pack2(os[g][tok][2*col], os[g][tok][2*col+1]);
      }
      __syncthreads();
      // ---- x += o @ Wo ----
      {
        const h2* wo = Wo + (size_t)l * (BH/2) * BH;
        float ao[NT] = {};
        #pragma unroll 4
        for (int j2 = 0; j2 < BH/2; j2++) {
          h2 w = wo[j2*BH + col];
          #pragma unroll
          for (int tok = 0; tok < NT; tok++)
            ao[tok] = fdot2(hpk[g][tok][j2], w, ao[tok]);
        }
        #pragma unroll
        for (int tok = 0; tok < NT; tok++) xs[g][tok][col] += ao[tok];
      }
      __syncthreads();
      // ---- ffn RMSNorm -> packed hpk ----
      for (int tok = 0; tok < NT; tok++) {
        float v  = xs[g][tok][col];
        float ss = group_sum(v * v);
        float sca = rsqrtf(ss * (1.0f / BH) + 1e-5f);
        if (col < BH/2) {
          float a = xs[g][tok][2*col]   * sca * ffn_norm[l*BH + 2*col];
          float b = xs[g][tok][2*col+1] * sca * ffn_norm[l*BH + 2*col+1];
          hpk[g][tok][col] = pack2(a, b);
        }
      }
      __syncthreads();
      // ---- x += gelu(h2 @ W1) @ W2 (per token) ----
      {
        const h2* w1 = W1 + (size_t)l * (BH/2) * (4*BH);
        const h2* w2 = W2 + (size_t)l * (2*BH) * BH;
        for (int tok = 0; tok < NT; tok++) {
          float a1[4] = {};
          #pragma unroll 4
          for (int j2 = 0; j2 < BH/2; j2++) {
            h2 hv = hpk[g][tok][j2];
            #pragma unroll
            for (int m = 0; m < 4; m++)
              a1[m] = fdot2(hv, w1[(size_t)j2 * (4*BH) + m*BH + col], a1[m]);
          }
          #pragma unroll
          for (int m = 0; m < 4; m++) {
            float z = a1[m];
            f1[g][m*BH + col] = 0.5f * z * (1.0f + erff(z * 0.7071067811865476f));
          }
          __syncthreads();
          // pack f1 (768 pairs per seq; 2 per thread)
          f1pk[g][col]       = pack2(f1[g][2*col],         f1[g][2*col + 1]);
          f1pk[g][col + GSZ] = pack2(f1[g][2*(col + GSZ)], f1[g][2*(col + GSZ) + 1]);
          __syncthreads();
          float a2 = 0.f;
          #pragma unroll 4
          for (int j2 = 0; j2 < 2*BH; j2++)
            a2 = fdot2(f1pk[g][j2], w2[(size_t)j2 * BH + col], a2);
          xs[g][tok][col] += a2;
          __syncthreads();
        }
      }
    }
  };

  for (int i = 0; i < S_CNT; i++) {
    int grow;
    if (i == 0) { layers(IC<4>{}, 0, true);           grow = 3; }
    else        { layers(IC<1>{}, PP + i - 1, false); grow = 0; }

    // ---- argmax over hidden dims (first-max tie-break like jnp.argmax) ----
    {
      float v = xs[g][grow][col]; int idx = col;
      #pragma unroll
      for (int off = 32; off; off >>= 1) {
        float v2 = __shfl_down(v, off, 64); int i2 = __shfl_down(idx, off, 64);
        if (v2 > v || (v2 == v && i2 < idx)) { v = v2; idx = i2; }
      }
      if ((tid & 63) == 0) { redv[tid >> 6] = v; redi[tid >> 6] = idx; }
      __syncthreads();
      if (col == 0) {
        const int base = g * 6;
        float bv = redv[base]; int bi = redi[base];
        for (int w = 1; w < 6; w++)
          if (redv[base+w] > bv || (redv[base+w] == bv && redi[base+w] < bi)) {
            bv = redv[base+w]; bi = redi[base+w];
          }
        amx[g] = bi;
      }
      __syncthreads();
    }
    // ---- pack gen row, then logits (zeroed if already finished) ----
    if (col < BH/2)
      hpk[g][0][col] = pack2(xs[g][grow][2*col], xs[g][grow][2*col+1]);
    __syncthreads();
    if (col < NV) {
      float acc = 0.f;
      #pragma unroll 4
      for (int j2 = 0; j2 < BH/2; j2++)
        acc = fdot2(hpk[g][0][j2], Wlm[(size_t)j2 * NV + col], acc);
      out[((size_t)seq * S_CNT + i) * NV + col] = fin[g] ? 0.0f : acc;
    }
    __syncthreads();
    // ---- next token = (finished ? 0 : gen); then update finished ----
    {
      float gv = xs[g][grow][col];
      xs[g][0][col] = fin[g] ? 0.0f : gv;
    }
    __syncthreads();
    if (tid < 2 && amx[tid] == EOS_I) fin[tid] = 1;
    __syncthreads();
  }
}

extern "C" void kernel_launch(void* const* d_in, const int* in_sizes, int n_in,
                              void* d_out, int out_size, void* d_ws, size_t ws_size,
                              hipStream_t stream) {
  const float* x     = (const float*)d_in[0];
  // d_in[1] = target (unused)
  const float* Wproj = (const float*)d_in[2];
  const float* an    = (const float*)d_in[3];
  const float* Wq    = (const float*)d_in[4];
  const float* Wk    = (const float*)d_in[5];
  const float* Wv    = (const float*)d_in[6];
  const float* Wo    = (const float*)d_in[7];
  const float* fn    = (const float*)d_in[8];
  const float* W1    = (const float*)d_in[9];
  const float* W2    = (const float*)d_in[10];
  const float* Wlm   = (const float*)d_in[11];
  float* out = (float*)d_out;
  (void)ws_size; (void)in_sizes; (void)n_in; (void)out_size;

  // ---- carve d_ws: packed half2 weights, then f16 KV ----
  h2* w = (h2*)d_ws;
  const int n_proj = (H_IN/2) * (PP*BH);      //   786,432 h2
  const int n_qkvo = NL * (BH/2) * BH;        //   294,912 h2 each
  const int n_w1   = NL * (BH/2) * (4*BH);    // 1,179,648 h2
  const int n_w2   = NL * (2*BH) * BH;        // 1,179,648 h2
  const int n_lm   = (BH/2) * NV;             //    49,536 h2
  h2* Wproj_p = w;  w += n_proj;
  h2* Wq_p    = w;  w += n_qkvo;
  h2* Wk_p    = w;  w += n_qkvo;
  h2* Wv_p    = w;  w += n_qkvo;
  h2* Wo_p    = w;  w += n_qkvo;
  h2* W1_p    = w;  w += n_w1;
  h2* W2_p    = w;  w += n_w2;
  h2* Wlm_p   = w;  w += n_lm;
  const size_t kv_elems = (size_t)NSEQ * NL * TT * BH;  // 12,582,912
  _Float16* kbuf = (_Float16*)w;
  _Float16* vbuf = kbuf + kv_elems;

  auto pack = [&](const float* src, h2* dst, int R, int C) {
    dim3 grid((C + 255) / 256, R / 2);
    pack_kernel<<<grid, 256, 0, stream>>>(src, dst, C);
  };
  pack(Wproj, Wproj_p, H_IN,      PP*BH);
  pack(Wq,    Wq_p,    NL*BH,     BH);
  pack(Wk,    Wk_p,    NL*BH,     BH);
  pack(Wv,    Wv_p,    NL*BH,     BH);
  pack(Wo,    Wo_p,    NL*BH,     BH);
  pack(W1,    W1_p,    NL*BH,     4*BH);
  pack(W2,    W2_p,    NL*4*BH,   BH);
  pack(Wlm,   Wlm_p,   BH,        NV);

  decoder_kernel<<<NSEQ / 2, NTH, 0, stream>>>(
      x, Wproj_p, an, Wq_p, Wk_p, Wv_p, Wo_p, fn, W1_p, W2_p, Wlm_p, out, kbuf, vbuf);
}

// Round 5
// 3706.177 us; speedup vs baseline: 1.9130x; 1.7474x over previous
//
#include <hip/hip_runtime.h>
#include <hip/hip_bf16.h>

// ByteLevelDecoder: B=2,S=256,H=1024, BH=384,NH=8,HD=48, P=4,S_C=12,L=4,V=258,T=16
// Persistent kernel, 1 block = 2 sequences, 384 threads; BOTH sequences share
// every weight load (2 uses/load). Weights repacked f32 -> h8 (8 x f16 along the
// reduction dim, 16B/lane global_load_dwordx4) -- attacks the measured invariant
// of ~12 cyc per wave-load-instruction (rounds 2/3/4 all had identical per-CU
// load-instr counts and identical times). Inner products via v_dot2_f32_f16.
// Activations f32/h2 in LDS; KV cache f16 in d_ws.

constexpr int H_IN  = 1024;
constexpr int BH    = 384;
constexpr int NH    = 8;
constexpr int HD    = 48;
constexpr int PP    = 4;
constexpr int S_CNT = 12;
constexpr int NL    = 4;
constexpr int NV    = 258;
constexpr int TT    = 16;
constexpr int NSEQ  = 512;
constexpr int EOS_I = 257;
constexpr int NTH   = 384;
constexpr float RSCALE = 0.14433756729740646f;  // 1/sqrt(48)

typedef _Float16 h2 __attribute__((ext_vector_type(2)));
typedef _Float16 h8 __attribute__((ext_vector_type(8)));

union W16 { h8 v8; h2 h[4]; _Float16 e[8]; };

template<int N> struct IC { static constexpr int value = N; };

__device__ __forceinline__ float fdot2(h2 a, h2 b, float c) {
#if __has_builtin(__builtin_amdgcn_fdot2)
  return __builtin_amdgcn_fdot2(a, b, c, false);
#else
  return c + (float)a.x * (float)b.x + (float)a.y * (float)b.y;
#endif
}

__device__ __forceinline__ h2 pack2(float a, float b) {
  h2 r; r.x = (_Float16)a; r.y = (_Float16)b; return r;
}

// ---- repack prepass: dst[j8*C + c] = {src[8*j8+r][c]}_{r=0..7}  (16B per elem) ----
__global__ __launch_bounds__(256)
void pack8_kernel(const float* __restrict__ src, h8* __restrict__ dst, int C) {
  int c  = blockIdx.x * 256 + threadIdx.x;
  int j8 = blockIdx.y;
  if (c < C) {
    h8 v;
    #pragma unroll
    for (int r = 0; r < 8; r++) v[r] = (_Float16)src[(size_t)(8 * j8 + r) * C + c];
    dst[(size_t)j8 * C + c] = v;
  }
}

__global__ __launch_bounds__(NTH)
void decoder_kernel(const float* __restrict__ x,
                    const h8* __restrict__ Wproj8,   // [128][1536]
                    const float* __restrict__ attn_norm,
                    const h8* __restrict__ Wq8,      // [l*48][384]
                    const h8* __restrict__ Wk8,
                    const h8* __restrict__ Wv8,
                    const h8* __restrict__ Wo8,
                    const float* __restrict__ ffn_norm,
                    const h8* __restrict__ W18,      // [l*48][1536]
                    const h8* __restrict__ W28,      // [l*192][384]
                    const h8* __restrict__ Wlm8,     // [48][258]
                    float* __restrict__ out,
                    _Float16* __restrict__ kbuf,
                    _Float16* __restrict__ vbuf)
{
  __shared__ float xs[2][4][BH];                        // residual stream
  __shared__ __align__(16) h2 hpk[2][4][BH/2];          // packed normed act / packed os
  __shared__ float qs[2][4][BH];
  __shared__ float os[2][4][BH];
  __shared__ float f1s[2][2][4*BH];                     // gelu out f32 (<=2 toks/pass)
  __shared__ __align__(16) h2 f1pk[2][2][2*BH];         // packed gelu out
  __shared__ __align__(16) h2 xpk[2][H_IN/2];           // packed input x
  __shared__ __align__(16) h2 genpk[2][BH/2];           // packed gen row for LM head
  __shared__ float sc[2][NH][4][TT];
  __shared__ float redsum[6];
  __shared__ float redv[6];
  __shared__ int   redi[6];
  __shared__ int   amx[2];
  __shared__ int   fin[2];

  const int tid  = threadIdx.x;
  const int col  = tid;
  const int seq0 = blockIdx.x * 2;

  auto block_sum = [&](float v) -> float {
    #pragma unroll
    for (int off = 32; off; off >>= 1) v += __shfl_down(v, off, 64);
    if ((tid & 63) == 0) redsum[tid >> 6] = v;
    __syncthreads();
    float s = redsum[0] + redsum[1] + redsum[2] + redsum[3] + redsum[4] + redsum[5];
    __syncthreads();
    return s;
  };

  if (tid < 2) fin[tid] = 0;

  // ---- stage packed x ----
  for (int s = 0; s < 2; s++) {
    const size_t base = (size_t)(seq0 + s) * H_IN;
    for (int j2 = tid; j2 < H_IN / 2; j2 += NTH)
      xpk[s][j2] = pack2(x[base + 2 * j2], x[base + 2 * j2 + 1]);
  }
  __syncthreads();
  // ---- x0 = (x_row @ Wproj).reshape(P, BH) ----
  {
    float acc[2][4] = {};
    for (int j8 = 0; j8 < H_IN / 8; j8++) {
      W16 w[4];
      #pragma unroll
      for (int m = 0; m < 4; m++) w[m].v8 = Wproj8[(size_t)j8 * (PP * BH) + m * BH + col];
      #pragma unroll
      for (int s = 0; s < 2; s++) {
        W16 hv; hv.v8 = *(const h8*)&xpk[s][j8 * 4];
        #pragma unroll
        for (int m = 0; m < 4; m++)
          #pragma unroll
          for (int r = 0; r < 4; r++)
            acc[s][m] = fdot2(hv.h[r], w[m].h[r], acc[s][m]);
      }
    }
    for (int s = 0; s < 2; s++)
      #pragma unroll
      for (int m = 0; m < 4; m++) xs[s][m][col] = acc[s][m];
  }
  __syncthreads();

  auto layers = [&](auto ntc, int pos, bool causal) {
    constexpr int NT = decltype(ntc)::value;
    const int nk = pos + NT;
    for (int l = 0; l < NL; l++) {
      // ---- attn RMSNorm -> packed hpk ----
      for (int s = 0; s < 2; s++)
        for (int tok = 0; tok < NT; tok++) {
          float v  = xs[s][tok][col];
          float ss = block_sum(v * v);
          float sca = rsqrtf(ss * (1.0f / BH) + 1e-5f);
          if (col < BH / 2) {
            float a = xs[s][tok][2 * col]     * sca * attn_norm[l * BH + 2 * col];
            float b = xs[s][tok][2 * col + 1] * sca * attn_norm[l * BH + 2 * col + 1];
            hpk[s][tok][col] = pack2(a, b);
          }
        }
      __syncthreads();
      // ---- q,k,v = h @ Wq/Wk/Wv ; write k,v to cache ----
      {
        const size_t wb = (size_t)l * 48 * BH + col;
        float aq[2][NT] = {}, ak[2][NT] = {}, av[2][NT] = {};
        #pragma unroll 2
        for (int j8 = 0; j8 < 48; j8++) {
          W16 wq, wk, wv;
          wq.v8 = Wq8[wb + (size_t)j8 * BH];
          wk.v8 = Wk8[wb + (size_t)j8 * BH];
          wv.v8 = Wv8[wb + (size_t)j8 * BH];
          #pragma unroll
          for (int s = 0; s < 2; s++)
            #pragma unroll
            for (int tok = 0; tok < NT; tok++) {
              W16 hv; hv.v8 = *(const h8*)&hpk[s][tok][j8 * 4];
              #pragma unroll
              for (int r = 0; r < 4; r++) {
                aq[s][tok] = fdot2(hv.h[r], wq.h[r], aq[s][tok]);
                ak[s][tok] = fdot2(hv.h[r], wk.h[r], ak[s][tok]);
                av[s][tok] = fdot2(hv.h[r], wv.h[r], av[s][tok]);
              }
            }
        }
        for (int s = 0; s < 2; s++) {
          const size_t cb = (((size_t)(seq0 + s) * NL + l) * TT + pos) * BH + col;
          #pragma unroll
          for (int tok = 0; tok < NT; tok++) {
            qs[s][tok][col] = aq[s][tok];
            kbuf[cb + (size_t)tok * BH] = (_Float16)ak[s][tok];
            vbuf[cb + (size_t)tok * BH] = (_Float16)av[s][tok];
          }
        }
      }
      __syncthreads();
      // ---- scores (<=256 lanes) ----
      {
        const int nu = 2 * NH * NT * nk;
        if (tid < nu) {
          int s = tid / (NH * NT * nk), r = tid % (NH * NT * nk);
          int h = r / (NT * nk); int r2 = r % (NT * nk);
          int qi = r2 / nk, j = r2 % nk;
          float d;
          if (causal && j > pos + qi) d = -1e30f;
          else {
            const h8* kp8 = (const h8*)(kbuf + (((size_t)(seq0 + s) * NL + l) * TT + j) * BH + h * HD);
            d = 0.f;
            #pragma unroll
            for (int c = 0; c < 6; c++) {
              W16 kk; kk.v8 = kp8[c];
              #pragma unroll
              for (int e = 0; e < 8; e++)
                d += qs[s][qi][h * HD + c * 8 + e] * (float)kk.e[e];
            }
            d *= RSCALE;
          }
          sc[s][h][qi][j] = d;
        }
      }
      __syncthreads();
      // ---- softmax over keys ----
      {
        const int nr = 2 * NH * NT;
        if (tid < nr) {
          int s = tid / (NH * NT), r = tid % (NH * NT);
          int h = r / NT, qi = r % NT;
          float m = -3.0e38f;
          for (int j = 0; j < nk; j++) m = fmaxf(m, sc[s][h][qi][j]);
          float den = 0.f;
          for (int j = 0; j < nk; j++) {
            float e = expf(sc[s][h][qi][j] - m);
            sc[s][h][qi][j] = e; den += e;
          }
          float inv = 1.0f / den;
          for (int j = 0; j < nk; j++) sc[s][h][qi][j] *= inv;
        }
      }
      __syncthreads();
      // ---- o = p @ V ----
      for (int s = 0; s < 2; s++) {
        const size_t vb = (((size_t)(seq0 + s) * NL + l) * TT) * BH + col;
        const int h = col / HD;
        #pragma unroll
        for (int tok = 0; tok < NT; tok++) {
          float acc = 0.f;
          for (int j = 0; j < nk; j++)
            acc += sc[s][h][tok][j] * (float)vbuf[vb + (size_t)j * BH];
          os[s][tok][col] = acc;
        }
      }
      __syncthreads();
      // ---- pack os -> hpk (both seqs at once: 384 threads = 2 x 192) ----
      {
        int ps = (col >= BH / 2) ? 1 : 0;
        int pc = col - ps * (BH / 2);
        #pragma unroll
        for (int tok = 0; tok < NT; tok++)
          hpk[ps][tok][pc] = pack2(os[ps][tok][2 * pc], os[ps][tok][2 * pc + 1]);
      }
      __syncthreads();
      // ---- x += o @ Wo ----
      {
        const size_t wb = (size_t)l * 48 * BH + col;
        float ao[2][NT] = {};
        #pragma unroll 2
        for (int j8 = 0; j8 < 48; j8++) {
          W16 w; w.v8 = Wo8[wb + (size_t)j8 * BH];
          #pragma unroll
          for (int s = 0; s < 2; s++)
            #pragma unroll
            for (int tok = 0; tok < NT; tok++) {
              W16 hv; hv.v8 = *(const h8*)&hpk[s][tok][j8 * 4];
              #pragma unroll
              for (int r = 0; r < 4; r++)
                ao[s][tok] = fdot2(hv.h[r], w.h[r], ao[s][tok]);
            }
        }
        #pragma unroll
        for (int s = 0; s < 2; s++)
          #pragma unroll
          for (int tok = 0; tok < NT; tok++) xs[s][tok][col] += ao[s][tok];
      }
      __syncthreads();
      // ---- ffn RMSNorm -> packed hpk ----
      for (int s = 0; s < 2; s++)
        for (int tok = 0; tok < NT; tok++) {
          float v  = xs[s][tok][col];
          float ss = block_sum(v * v);
          float sca = rsqrtf(ss * (1.0f / BH) + 1e-5f);
          if (col < BH / 2) {
            float a = xs[s][tok][2 * col]     * sca * ffn_norm[l * BH + 2 * col];
            float b = xs[s][tok][2 * col + 1] * sca * ffn_norm[l * BH + 2 * col + 1];
            hpk[s][tok][col] = pack2(a, b);
          }
        }
      __syncthreads();
      // ---- x += gelu(h @ W1) @ W2  (passes of TO tokens; weights loaded once/pass) ----
      {
        constexpr int TO = (NT == 4) ? 2 : 1;
        for (int t0 = 0; t0 < NT; t0 += TO) {
          float a1[2][TO][4] = {};
          for (int j8 = 0; j8 < 48; j8++) {
            W16 w[4];
            #pragma unroll
            for (int m = 0; m < 4; m++)
              w[m].v8 = W18[(size_t)(l * 48 + j8) * (4 * BH) + m * BH + col];
            #pragma unroll
            for (int s = 0; s < 2; s++)
              #pragma unroll
              for (int t = 0; t < TO; t++) {
                W16 hv; hv.v8 = *(const h8*)&hpk[s][t0 + t][j8 * 4];
                #pragma unroll
                for (int m = 0; m < 4; m++)
                  #pragma unroll
                  for (int r = 0; r < 4; r++)
                    a1[s][t][m] = fdot2(hv.h[r], w[m].h[r], a1[s][t][m]);
              }
          }
          #pragma unroll
          for (int s = 0; s < 2; s++)
            #pragma unroll
            for (int t = 0; t < TO; t++)
              #pragma unroll
              for (int m = 0; m < 4; m++) {
                float z = a1[s][t][m];
                f1s[s][t][m * BH + col] = 0.5f * z * (1.0f + erff(z * 0.7071067811865476f));
              }
          __syncthreads();
          // pack f1s -> f1pk
          {
            const int total = 2 * TO * (2 * BH);
            for (int p = tid; p < total; p += NTH) {
              int s = p / (TO * 2 * BH); int rem = p - s * (TO * 2 * BH);
              int t = rem / (2 * BH);    int c2  = rem - t * (2 * BH);
              f1pk[s][t][c2] = pack2(f1s[s][t][2 * c2], f1s[s][t][2 * c2 + 1]);
            }
          }
          __syncthreads();
          float a2[2][TO] = {};
          #pragma unroll 4
          for (int j8 = 0; j8 < 192; j8++) {
            W16 w; w.v8 = W28[(size_t)(l * 192 + j8) * BH + col];
            #pragma unroll
            for (int s = 0; s < 2; s++)
              #pragma unroll
              for (int t = 0; t < TO; t++) {
                W16 fv; fv.v8 = *(const h8*)&f1pk[s][t][j8 * 4];
                #pragma unroll
                for (int r = 0; r < 4; r++)
                  a2[s][t] = fdot2(fv.h[r], w.h[r], a2[s][t]);
              }
          }
          #pragma unroll
          for (int s = 0; s < 2; s++)
            #pragma unroll
            for (int t = 0; t < TO; t++) xs[s][t0 + t][col] += a2[s][t];
          __syncthreads();
        }
      }
    }
  };

  for (int i = 0; i < S_CNT; i++) {
    int grow;
    if (i == 0) { layers(IC<4>{}, 0, true);           grow = 3; }
    else        { layers(IC<1>{}, PP + i - 1, false); grow = 0; }

    // ---- argmax over hidden dims (first-max tie-break like jnp.argmax) ----
    for (int s = 0; s < 2; s++) {
      float v = xs[s][grow][col]; int idx = col;
      #pragma unroll
      for (int off = 32; off; off >>= 1) {
        float v2 = __shfl_down(v, off, 64); int i2 = __shfl_down(idx, off, 64);
        if (v2 > v || (v2 == v && i2 < idx)) { v = v2; idx = i2; }
      }
      if ((tid & 63) == 0) { redv[tid >> 6] = v; redi[tid >> 6] = idx; }
      __syncthreads();
      if (tid == 0) {
        float bv = redv[0]; int bi = redi[0];
        for (int w = 1; w < 6; w++)
          if (redv[w] > bv || (redv[w] == bv && redi[w] < bi)) { bv = redv[w]; bi = redi[w]; }
        amx[s] = bi;
      }
      __syncthreads();
    }
    // ---- pack gen rows (both seqs), then logits ----
    {
      int ps = (col >= BH / 2) ? 1 : 0;
      int pc = col - ps * (BH / 2);
      genpk[ps][pc] = pack2(xs[ps][grow][2 * pc], xs[ps][grow][2 * pc + 1]);
    }
    __syncthreads();
    for (int s = 0; s < 2; s++) {
      if (col < NV) {
        float acc = 0.f;
        #pragma unroll 4
        for (int j8 = 0; j8 < 48; j8++) {
          W16 w; w.v8 = Wlm8[(size_t)j8 * NV + col];
          W16 gv; gv.v8 = *(const h8*)&genpk[s][j8 * 4];
          #pragma unroll
          for (int r = 0; r < 4; r++) acc = fdot2(gv.h[r], w.h[r], acc);
        }
        out[((size_t)(seq0 + s) * S_CNT + i) * NV + col] = fin[s] ? 0.0f : acc;
      }
    }
    __syncthreads();
    // ---- next token = (finished ? 0 : gen); then update finished ----
    for (int s = 0; s < 2; s++) {
      float gv = xs[s][grow][col];
      xs[s][0][col] = fin[s] ? 0.0f : gv;
    }
    __syncthreads();
    if (tid < 2 && amx[tid] == EOS_I) fin[tid] = 1;
    __syncthreads();
  }
}

extern "C" void kernel_launch(void* const* d_in, const int* in_sizes, int n_in,
                              void* d_out, int out_size, void* d_ws, size_t ws_size,
                              hipStream_t stream) {
  const float* x     = (const float*)d_in[0];
  // d_in[1] = target (unused)
  const float* Wproj = (const float*)d_in[2];
  const float* an    = (const float*)d_in[3];
  const float* Wq    = (const float*)d_in[4];
  const float* Wk    = (const float*)d_in[5];
  const float* Wv    = (const float*)d_in[6];
  const float* Wo    = (const float*)d_in[7];
  const float* fn    = (const float*)d_in[8];
  const float* W1    = (const float*)d_in[9];
  const float* W2    = (const float*)d_in[10];
  const float* Wlm   = (const float*)d_in[11];
  float* out = (float*)d_out;
  (void)ws_size; (void)in_sizes; (void)n_in; (void)out_size;

  // ---- carve d_ws: h8-packed weights, then f16 KV ----
  h8* w = (h8*)d_ws;
  const int n_proj = (H_IN / 8) * (PP * BH);      // 196,608
  const int n_qkvo = NL * (BH / 8) * BH;          //  73,728 each
  const int n_w1   = NL * (BH / 8) * (4 * BH);    // 294,912
  const int n_w2   = NL * (4 * BH / 8) * BH;      // 294,912
  const int n_lm   = (BH / 8) * NV;               //  12,384
  h8* Wproj_p = w;  w += n_proj;
  h8* Wq_p    = w;  w += n_qkvo;
  h8* Wk_p    = w;  w += n_qkvo;
  h8* Wv_p    = w;  w += n_qkvo;
  h8* Wo_p    = w;  w += n_qkvo;
  h8* W1_p    = w;  w += n_w1;
  h8* W2_p    = w;  w += n_w2;
  h8* Wlm_p   = w;  w += n_lm;
  const size_t kv_elems = (size_t)NSEQ * NL * TT * BH;  // 12,582,912
  _Float16* kbuf = (_Float16*)w;
  _Float16* vbuf = kbuf + kv_elems;

  auto pack = [&](const float* src, h8* dst, int R, int C) {
    dim3 grid((C + 255) / 256, R / 8);
    pack8_kernel<<<grid, 256, 0, stream>>>(src, dst, C);
  };
  pack(Wproj, Wproj_p, H_IN,        PP * BH);
  pack(Wq,    Wq_p,    NL * BH,     BH);
  pack(Wk,    Wk_p,    NL * BH,     BH);
  pack(Wv,    Wv_p,    NL * BH,     BH);
  pack(Wo,    Wo_p,    NL * BH,     BH);
  pack(W1,    W1_p,    NL * BH,     4 * BH);
  pack(W2,    W2_p,    NL * 4 * BH, BH);
  pack(Wlm,   Wlm_p,   BH,          NV);

  decoder_kernel<<<NSEQ / 2, NTH, 0, stream>>>(
      x, Wproj_p, an, Wq_p, Wk_p, Wv_p, Wo_p, fn, W1_p, W2_p, Wlm_p, out, kbuf, vbuf);
}

// Round 6
// 2450.142 us; speedup vs baseline: 2.8937x; 1.5126x over previous
//
#include <hip/hip_runtime.h>
#include <hip/hip_bf16.h>

// ByteLevelDecoder: B=2,S=256,H=1024, BH=384,NH=8,HD=48, P=4,S_C=12,L=4,V=258,T=16
// Persistent kernel, 1 block = 2 sequences, 768 threads = 12 waves/CU.
// Split-K: for 384-col GEMMs (QKV/Wo/W2), group g = tid/384 owns reduction half g
// (disjoint weight rows -> per-block weight traffic stays 1x, occupancy 2x vs r5).
// For 1536-col GEMMs (Wproj/W1), each thread owns 2 columns, full K.
// Weights h8-packed (16B loads) in d_ws; activations stored as f16 scalars in LDS,
// read back as h8; inner products via v_dot2_f32_f16. KV cache f16 in d_ws.

constexpr int H_IN  = 1024;
constexpr int BH    = 384;
constexpr int NH    = 8;
constexpr int HD    = 48;
constexpr int PP    = 4;
constexpr int S_CNT = 12;
constexpr int NL    = 4;
constexpr int NV    = 258;
constexpr int TT    = 16;
constexpr int NSEQ  = 512;
constexpr int EOS_I = 257;
constexpr int NTH   = 768;
constexpr float RSCALE = 0.14433756729740646f;  // 1/sqrt(48)

typedef _Float16 h2 __attribute__((ext_vector_type(2)));
typedef _Float16 h8 __attribute__((ext_vector_type(8)));

union W16 { h8 v8; h2 h[4]; _Float16 e[8]; };

template<int N> struct IC { static constexpr int value = N; };

__device__ __forceinline__ float fdot2(h2 a, h2 b, float c) {
#if __has_builtin(__builtin_amdgcn_fdot2)
  return __builtin_amdgcn_fdot2(a, b, c, false);
#else
  return c + (float)a.x * (float)b.x + (float)a.y * (float)b.y;
#endif
}

// ---- repack prepass: dst[j8*C + c] = {src[8*j8+r][c]}_{r=0..7} ----
__global__ __launch_bounds__(256)
void pack8_kernel(const float* __restrict__ src, h8* __restrict__ dst, int C) {
  int c  = blockIdx.x * 256 + threadIdx.x;
  int j8 = blockIdx.y;
  if (c < C) {
    h8 v;
    #pragma unroll
    for (int r = 0; r < 8; r++) v[r] = (_Float16)src[(size_t)(8 * j8 + r) * C + c];
    dst[(size_t)j8 * C + c] = v;
  }
}

__global__ __launch_bounds__(NTH)
void decoder_kernel(const float* __restrict__ x,
                    const h8* __restrict__ Wproj8,   // [128][1536]
                    const float* __restrict__ attn_norm,
                    const h8* __restrict__ Wq8,      // [l*48][384]
                    const h8* __restrict__ Wk8,
                    const h8* __restrict__ Wv8,
                    const h8* __restrict__ Wo8,
                    const float* __restrict__ ffn_norm,
                    const h8* __restrict__ W18,      // [l*48][1536]
                    const h8* __restrict__ W28,      // [l*192][384]
                    const h8* __restrict__ Wlm8,     // [48][258]
                    float* __restrict__ out,
                    _Float16* __restrict__ kbuf,
                    _Float16* __restrict__ vbuf)
{
  __shared__ float xs[2][4][BH];                          // residual stream (f32)
  __shared__ __align__(16) _Float16 hh[2][4][BH];         // normed activations (f16)
  __shared__ __align__(16) _Float16 qh[2][4][BH];         // q (f16)
  __shared__ __align__(16) _Float16 oh[2][4][BH];         // attention out (f16)
  __shared__ __align__(16) _Float16 xh[2][H_IN];          // input x (f16)
  __shared__ __align__(16) _Float16 genh[2][BH];          // gen row (f16)
  __shared__ float sc[2][NH][4][TT];
  __shared__ union Scr {
    float qkvp[3][2][4][BH];                              // QKV split-K partials (36KB)
    float wop[2][4][BH];                                  // Wo partials (12KB)
    struct { __align__(16) _Float16 f1h[2][2][4*BH];      // gelu out f16 (12KB)
             float w2p[2][2][BH]; } ffn;                  // W2 partials (6KB)
  } scr;
  __shared__ float redsum[4][12];
  __shared__ float redv[12];
  __shared__ int   redi[12];
  __shared__ int   amx[2];
  __shared__ int   fin[2];

  const int tid = threadIdx.x;
  const int kg  = tid / BH;        // split-K group (0/1); also seq index in seq-mapped phases
  const int col = tid - kg * BH;   // 0..383
  const int sq  = kg;              // alias for readability in seq-mapped phases
  const int wid = tid >> 6;        // wave id 0..11 (waves 0-5 <-> sq 0, 6-11 <-> sq 1)
  const int seq0 = blockIdx.x * 2;

  if (tid < 2) fin[tid] = 0;

  // ---- stage x as f16 ----
  for (int s = 0; s < 2; s++) {
    const size_t base = (size_t)(seq0 + s) * H_IN;
    for (int j = tid; j < H_IN; j += NTH) xh[s][j] = (_Float16)x[base + j];
  }
  __syncthreads();
  // ---- x0 = (x_row @ Wproj).reshape(P, BH): thread owns cols {tid, tid+768} ----
  {
    float acc[2][2] = {};
    #pragma unroll 2
    for (int j8 = 0; j8 < H_IN / 8; j8++) {
      W16 w0, w1;
      w0.v8 = Wproj8[(size_t)j8 * (PP * BH) + tid];
      w1.v8 = Wproj8[(size_t)j8 * (PP * BH) + tid + NTH];
      #pragma unroll
      for (int s = 0; s < 2; s++) {
        W16 hv; hv.v8 = *(const h8*)&xh[s][j8 * 8];
        #pragma unroll
        for (int r = 0; r < 4; r++) {
          acc[s][0] = fdot2(hv.h[r], w0.h[r], acc[s][0]);
          acc[s][1] = fdot2(hv.h[r], w1.h[r], acc[s][1]);
        }
      }
    }
    const int m0 = tid / BH, cc = tid % BH;       // col tid   -> (m0, cc)
    for (int s = 0; s < 2; s++) {
      xs[s][m0][cc]     = acc[s][0];
      xs[s][m0 + 2][cc] = acc[s][1];              // col tid+768 -> (m0+2, cc)
    }
  }
  __syncthreads();

  auto layers = [&](auto ntc, int pos, bool causal) {
    constexpr int NT = decltype(ntc)::value;
    constexpr int TO = (NT == 4) ? 2 : 1;
    const int nk = pos + NT;
    for (int l = 0; l < NL; l++) {
      // ==== attn RMSNorm -> hh (thread = (sq, col); both seqs in parallel) ====
      {
        #pragma unroll
        for (int tok = 0; tok < NT; tok++) {
          float r = xs[sq][tok][col]; r *= r;
          #pragma unroll
          for (int off = 32; off; off >>= 1) r += __shfl_down(r, off, 64);
          if ((tid & 63) == 0) redsum[tok][wid] = r;
        }
        __syncthreads();
        const int b = sq * 6;
        #pragma unroll
        for (int tok = 0; tok < NT; tok++) {
          float ss = redsum[tok][b] + redsum[tok][b+1] + redsum[tok][b+2] +
                     redsum[tok][b+3] + redsum[tok][b+4] + redsum[tok][b+5];
          float sca = rsqrtf(ss * (1.0f / BH) + 1e-5f);
          hh[sq][tok][col] = (_Float16)(xs[sq][tok][col] * sca * attn_norm[l * BH + col]);
        }
        __syncthreads();
      }
      // ==== q,k,v = h @ Wq/Wk/Wv (split-K: group kg owns rows [kg*192,kg*192+192)) ====
      {
        const size_t wb = ((size_t)l * 48 + kg * 24) * BH + col;
        float aq[2][NT] = {}, ak[2][NT] = {}, av[2][NT] = {};
        #pragma unroll 2
        for (int j8 = 0; j8 < 24; j8++) {
          W16 wq, wk, wv;
          wq.v8 = Wq8[wb + (size_t)j8 * BH];
          wk.v8 = Wk8[wb + (size_t)j8 * BH];
          wv.v8 = Wv8[wb + (size_t)j8 * BH];
          #pragma unroll
          for (int s = 0; s < 2; s++)
            #pragma unroll
            for (int tok = 0; tok < NT; tok++) {
              W16 hv; hv.v8 = *(const h8*)&hh[s][tok][(kg * 24 + j8) * 8];
              #pragma unroll
              for (int r = 0; r < 4; r++) {
                aq[s][tok] = fdot2(hv.h[r], wq.h[r], aq[s][tok]);
                ak[s][tok] = fdot2(hv.h[r], wk.h[r], ak[s][tok]);
                av[s][tok] = fdot2(hv.h[r], wv.h[r], av[s][tok]);
              }
            }
        }
        if (kg == 1) {
          #pragma unroll
          for (int s = 0; s < 2; s++)
            #pragma unroll
            for (int tok = 0; tok < NT; tok++) {
              scr.qkvp[0][s][tok][col] = aq[s][tok];
              scr.qkvp[1][s][tok][col] = ak[s][tok];
              scr.qkvp[2][s][tok][col] = av[s][tok];
            }
        }
        __syncthreads();
        if (kg == 0) {
          #pragma unroll
          for (int s = 0; s < 2; s++) {
            const size_t cb = (((size_t)(seq0 + s) * NL + l) * TT + pos) * BH + col;
            #pragma unroll
            for (int tok = 0; tok < NT; tok++) {
              qh[s][tok][col] = (_Float16)(aq[s][tok] + scr.qkvp[0][s][tok][col]);
              kbuf[cb + (size_t)tok * BH] = (_Float16)(ak[s][tok] + scr.qkvp[1][s][tok][col]);
              vbuf[cb + (size_t)tok * BH] = (_Float16)(av[s][tok] + scr.qkvp[2][s][tok][col]);
            }
          }
        }
        __syncthreads();
      }
      // ==== scores ====
      {
        const int nu = 2 * NH * NT * nk;   // <= 256
        if (tid < nu) {
          int s = tid / (NH * NT * nk), r = tid % (NH * NT * nk);
          int h = r / (NT * nk); int r2 = r % (NT * nk);
          int qi = r2 / nk, j = r2 % nk;
          float d;
          if (causal && j > pos + qi) d = -1e30f;
          else {
            const h8* kp8 = (const h8*)(kbuf + (((size_t)(seq0 + s) * NL + l) * TT + j) * BH + h * HD);
            d = 0.f;
            #pragma unroll
            for (int c = 0; c < 6; c++) {
              W16 kk; kk.v8 = kp8[c];
              #pragma unroll
              for (int e = 0; e < 8; e++)
                d += (float)qh[s][qi][h * HD + c * 8 + e] * (float)kk.e[e];
            }
            d *= RSCALE;
          }
          sc[s][h][qi][j] = d;
        }
      }
      __syncthreads();
      // ==== softmax over keys ====
      {
        const int nr = 2 * NH * NT;
        if (tid < nr) {
          int s = tid / (NH * NT), r = tid % (NH * NT);
          int h = r / NT, qi = r % NT;
          float m = -3.0e38f;
          for (int j = 0; j < nk; j++) m = fmaxf(m, sc[s][h][qi][j]);
          float den = 0.f;
          for (int j = 0; j < nk; j++) {
            float e = expf(sc[s][h][qi][j] - m);
            sc[s][h][qi][j] = e; den += e;
          }
          float inv = 1.0f / den;
          for (int j = 0; j < nk; j++) sc[s][h][qi][j] *= inv;
        }
      }
      __syncthreads();
      // ==== o = p @ V  (thread = (sq, col)) ====
      {
        const size_t vb = (((size_t)(seq0 + sq) * NL + l) * TT) * BH + col;
        const int h = col / HD;
        #pragma unroll
        for (int tok = 0; tok < NT; tok++) {
          float acc = 0.f;
          for (int j = 0; j < nk; j++)
            acc += sc[sq][h][tok][j] * (float)vbuf[vb + (size_t)j * BH];
          oh[sq][tok][col] = (_Float16)acc;
        }
      }
      __syncthreads();
      // ==== x += o @ Wo (split-K) ====
      {
        const size_t wb = ((size_t)l * 48 + kg * 24) * BH + col;
        float ao[2][NT] = {};
        #pragma unroll 2
        for (int j8 = 0; j8 < 24; j8++) {
          W16 w; w.v8 = Wo8[wb + (size_t)j8 * BH];
          #pragma unroll
          for (int s = 0; s < 2; s++)
            #pragma unroll
            for (int tok = 0; tok < NT; tok++) {
              W16 hv; hv.v8 = *(const h8*)&oh[s][tok][(kg * 24 + j8) * 8];
              #pragma unroll
              for (int r = 0; r < 4; r++)
                ao[s][tok] = fdot2(hv.h[r], w.h[r], ao[s][tok]);
            }
        }
        if (kg == 1) {
          #pragma unroll
          for (int s = 0; s < 2; s++)
            #pragma unroll
            for (int tok = 0; tok < NT; tok++) scr.wop[s][tok][col] = ao[s][tok];
        }
        __syncthreads();
        if (kg == 0) {
          #pragma unroll
          for (int s = 0; s < 2; s++)
            #pragma unroll
            for (int tok = 0; tok < NT; tok++)
              xs[s][tok][col] += ao[s][tok] + scr.wop[s][tok][col];
        }
        __syncthreads();
      }
      // ==== ffn RMSNorm -> hh ====
      {
        #pragma unroll
        for (int tok = 0; tok < NT; tok++) {
          float r = xs[sq][tok][col]; r *= r;
          #pragma unroll
          for (int off = 32; off; off >>= 1) r += __shfl_down(r, off, 64);
          if ((tid & 63) == 0) redsum[tok][wid] = r;
        }
        __syncthreads();
        const int b = sq * 6;
        #pragma unroll
        for (int tok = 0; tok < NT; tok++) {
          float ss = redsum[tok][b] + redsum[tok][b+1] + redsum[tok][b+2] +
                     redsum[tok][b+3] + redsum[tok][b+4] + redsum[tok][b+5];
          float sca = rsqrtf(ss * (1.0f / BH) + 1e-5f);
          hh[sq][tok][col] = (_Float16)(xs[sq][tok][col] * sca * ffn_norm[l * BH + col]);
        }
        __syncthreads();
      }
      // ==== x += gelu(h @ W1) @ W2 (passes of TO tokens) ====
      for (int t0 = 0; t0 < NT; t0 += TO) {
        // W1: thread owns cols {tid, tid+768}, full K
        {
          float a1[2][TO][2] = {};
          #pragma unroll 2
          for (int j8 = 0; j8 < 48; j8++) {
            W16 w0, w1;
            w0.v8 = W18[((size_t)(l * 48 + j8)) * (4 * BH) + tid];
            w1.v8 = W18[((size_t)(l * 48 + j8)) * (4 * BH) + tid + NTH];
            #pragma unroll
            for (int s = 0; s < 2; s++)
              #pragma unroll
              for (int t = 0; t < TO; t++) {
                W16 hv; hv.v8 = *(const h8*)&hh[s][t0 + t][j8 * 8];
                #pragma unroll
                for (int r = 0; r < 4; r++) {
                  a1[s][t][0] = fdot2(hv.h[r], w0.h[r], a1[s][t][0]);
                  a1[s][t][1] = fdot2(hv.h[r], w1.h[r], a1[s][t][1]);
                }
              }
          }
          #pragma unroll
          for (int s = 0; s < 2; s++)
            #pragma unroll
            for (int t = 0; t < TO; t++) {
              float z0 = a1[s][t][0], z1 = a1[s][t][1];
              scr.ffn.f1h[s][t][tid]       = (_Float16)(0.5f * z0 * (1.0f + erff(z0 * 0.7071067811865476f)));
              scr.ffn.f1h[s][t][tid + NTH] = (_Float16)(0.5f * z1 * (1.0f + erff(z1 * 0.7071067811865476f)));
            }
          __syncthreads();
        }
        // W2: split-K (group kg owns rows [kg*768, kg*768+768))
        {
          float a2[2][TO] = {};
          #pragma unroll 4
          for (int j8 = 0; j8 < 96; j8++) {
            W16 w; w.v8 = W28[((size_t)(l * 192 + kg * 96 + j8)) * BH + col];
            #pragma unroll
            for (int s = 0; s < 2; s++)
              #pragma unroll
              for (int t = 0; t < TO; t++) {
                W16 fv; fv.v8 = *(const h8*)&scr.ffn.f1h[s][t][(kg * 96 + j8) * 8];
                #pragma unroll
                for (int r = 0; r < 4; r++)
                  a2[s][t] = fdot2(fv.h[r], w.h[r], a2[s][t]);
              }
          }
          if (kg == 1) {
            #pragma unroll
            for (int s = 0; s < 2; s++)
              #pragma unroll
              for (int t = 0; t < TO; t++) scr.ffn.w2p[s][t][col] = a2[s][t];
          }
          __syncthreads();
          if (kg == 0) {
            #pragma unroll
            for (int s = 0; s < 2; s++)
              #pragma unroll
              for (int t = 0; t < TO; t++)
                xs[s][t0 + t][col] += a2[s][t] + scr.ffn.w2p[s][t][col];
          }
          __syncthreads();
        }
      }
    }
  };

  for (int i = 0; i < S_CNT; i++) {
    int grow;
    if (i == 0) { layers(IC<4>{}, 0, true);           grow = 3; }
    else        { layers(IC<1>{}, PP + i - 1, false); grow = 0; }

    // ---- argmax over hidden dims (both seqs in parallel; first-max tie-break) ----
    {
      float v = xs[sq][grow][col]; int idx = col;
      #pragma unroll
      for (int off = 32; off; off >>= 1) {
        float v2 = __shfl_down(v, off, 64); int i2 = __shfl_down(idx, off, 64);
        if (v2 > v || (v2 == v && i2 < idx)) { v = v2; idx = i2; }
      }
      if ((tid & 63) == 0) { redv[wid] = v; redi[wid] = idx; }
      __syncthreads();
      if (col == 0) {
        const int b = sq * 6;
        float bv = redv[b]; int bi = redi[b];
        for (int w = 1; w < 6; w++)
          if (redv[b + w] > bv || (redv[b + w] == bv && redi[b + w] < bi)) {
            bv = redv[b + w]; bi = redi[b + w];
          }
        amx[sq] = bi;
      }
      // stage gen row as f16 for the LM head
      genh[sq][col] = (_Float16)xs[sq][grow][col];
      __syncthreads();
    }
    // ---- logits (zeroed if already finished) ----
    if (col < NV) {
      float acc = 0.f;
      #pragma unroll 4
      for (int j8 = 0; j8 < 48; j8++) {
        W16 w; w.v8 = Wlm8[(size_t)j8 * NV + col];
        W16 gv; gv.v8 = *(const h8*)&genh[sq][j8 * 8];
        #pragma unroll
        for (int r = 0; r < 4; r++) acc = fdot2(gv.h[r], w.h[r], acc);
      }
      out[((size_t)(seq0 + sq) * S_CNT + i) * NV + col] = fin[sq] ? 0.0f : acc;
    }
    __syncthreads();
    // ---- next token = (finished ? 0 : gen); then update finished ----
    {
      float gv = xs[sq][grow][col];
      xs[sq][0][col] = fin[sq] ? 0.0f : gv;
    }
    __syncthreads();
    if (tid < 2 && amx[tid] == EOS_I) fin[tid] = 1;
    __syncthreads();
  }
}

extern "C" void kernel_launch(void* const* d_in, const int* in_sizes, int n_in,
                              void* d_out, int out_size, void* d_ws, size_t ws_size,
                              hipStream_t stream) {
  const float* x     = (const float*)d_in[0];
  // d_in[1] = target (unused)
  const float* Wproj = (const float*)d_in[2];
  const float* an    = (const float*)d_in[3];
  const float* Wq    = (const float*)d_in[4];
  const float* Wk    = (const float*)d_in[5];
  const float* Wv    = (const float*)d_in[6];
  const float* Wo    = (const float*)d_in[7];
  const float* fn    = (const float*)d_in[8];
  const float* W1    = (const float*)d_in[9];
  const float* W2    = (const float*)d_in[10];
  const float* Wlm   = (const float*)d_in[11];
  float* out = (float*)d_out;
  (void)ws_size; (void)in_sizes; (void)n_in; (void)out_size;

  // ---- carve d_ws: h8-packed weights, then f16 KV ----
  h8* w = (h8*)d_ws;
  const int n_proj = (H_IN / 8) * (PP * BH);      // 196,608
  const int n_qkvo = NL * (BH / 8) * BH;          //  73,728 each
  const int n_w1   = NL * (BH / 8) * (4 * BH);    // 294,912
  const int n_w2   = NL * (4 * BH / 8) * BH;      // 294,912
  const int n_lm   = (BH / 8) * NV;               //  12,384
  h8* Wproj_p = w;  w += n_proj;
  h8* Wq_p    = w;  w += n_qkvo;
  h8* Wk_p    = w;  w += n_qkvo;
  h8* Wv_p    = w;  w += n_qkvo;
  h8* Wo_p    = w;  w += n_qkvo;
  h8* W1_p    = w;  w += n_w1;
  h8* W2_p    = w;  w += n_w2;
  h8* Wlm_p   = w;  w += n_lm;
  const size_t kv_elems = (size_t)NSEQ * NL * TT * BH;  // 12,582,912
  _Float16* kbuf = (_Float16*)w;
  _Float16* vbuf = kbuf + kv_elems;

  auto pack = [&](const float* src, h8* dst, int R, int C) {
    dim3 grid((C + 255) / 256, R / 8);
    pack8_kernel<<<grid, 256, 0, stream>>>(src, dst, C);
  };
  pack(Wproj, Wproj_p, H_IN,        PP * BH);
  pack(Wq,    Wq_p,    NL * BH,     BH);
  pack(Wk,    Wk_p,    NL * BH,     BH);
  pack(Wv,    Wv_p,    NL * BH,     BH);
  pack(Wo,    Wo_p,    NL * BH,     BH);
  pack(W1,    W1_p,    NL * BH,     4 * BH);
  pack(W2,    W2_p,    NL * 4 * BH, BH);
  pack(Wlm,   Wlm_p,   BH,          NV);

  decoder_kernel<<<NSEQ / 2, NTH, 0, stream>>>(
      x, Wproj_p, an, Wq_p, Wk_p, Wv_p, Wo_p, fn, W1_p, W2_p, Wlm_p, out, kbuf, vbuf);
}

// Round 7
// 2432.893 us; speedup vs baseline: 2.9142x; 1.0071x over previous
//
#include <hip/hip_runtime.h>
#include <hip/hip_bf16.h>

// ByteLevelDecoder: B=2,S=256,H=1024, BH=384,NH=8,HD=48, P=4,S_C=12,L=4,V=258,T=16
// Persistent kernel, 1 block = 2 sequences, 768 threads = 12 waves/CU.
// Split-K for 384-col GEMMs (QKV/Wo/W2): group kg = tid/384 owns reduction half.
// Round 7: batched-issue register prefetch in all weight GEMMs (U=4..8 loads
// hoisted per round -> 24-36 outstanding loads/SIMD, covering ~300cyc L2 latency),
// prefill FFN in a single 4-token pass, batched o=pV loads.
// Weights h8-packed (16B loads) in d_ws; activations f16 in LDS; KV f16 in d_ws.

constexpr int H_IN  = 1024;
constexpr int BH    = 384;
constexpr int NH    = 8;
constexpr int HD    = 48;
constexpr int PP    = 4;
constexpr int S_CNT = 12;
constexpr int NL    = 4;
constexpr int NV    = 258;
constexpr int TT    = 16;
constexpr int NSEQ  = 512;
constexpr int EOS_I = 257;
constexpr int NTH   = 768;
constexpr float RSCALE = 0.14433756729740646f;  // 1/sqrt(48)

typedef _Float16 h2 __attribute__((ext_vector_type(2)));
typedef _Float16 h8 __attribute__((ext_vector_type(8)));

union W16 { h8 v8; h2 h[4]; _Float16 e[8]; };

template<int N> struct IC { static constexpr int value = N; };

__device__ __forceinline__ float fdot2(h2 a, h2 b, float c) {
#if __has_builtin(__builtin_amdgcn_fdot2)
  return __builtin_amdgcn_fdot2(a, b, c, false);
#else
  return c + (float)a.x * (float)b.x + (float)a.y * (float)b.y;
#endif
}

// ---- repack prepass: dst[j8*C + c] = {src[8*j8+r][c]}_{r=0..7} ----
__global__ __launch_bounds__(256)
void pack8_kernel(const float* __restrict__ src, h8* __restrict__ dst, int C) {
  int c  = blockIdx.x * 256 + threadIdx.x;
  int j8 = blockIdx.y;
  if (c < C) {
    h8 v;
    #pragma unroll
    for (int r = 0; r < 8; r++) v[r] = (_Float16)src[(size_t)(8 * j8 + r) * C + c];
    dst[(size_t)j8 * C + c] = v;
  }
}

__global__ __launch_bounds__(NTH)
void decoder_kernel(const float* __restrict__ x,
                    const h8* __restrict__ Wproj8,   // [128][1536]
                    const float* __restrict__ attn_norm,
                    const h8* __restrict__ Wq8,      // [l*48][384]
                    const h8* __restrict__ Wk8,
                    const h8* __restrict__ Wv8,
                    const h8* __restrict__ Wo8,
                    const float* __restrict__ ffn_norm,
                    const h8* __restrict__ W18,      // [l*48][1536]
                    const h8* __restrict__ W28,      // [l*192][384]
                    const h8* __restrict__ Wlm8,     // [48][258]
                    float* __restrict__ out,
                    _Float16* __restrict__ kbuf,
                    _Float16* __restrict__ vbuf)
{
  __shared__ float xs[2][4][BH];                          // residual stream (f32)
  __shared__ __align__(16) _Float16 hh[2][4][BH];         // normed activations (f16)
  __shared__ __align__(16) _Float16 qh[2][4][BH];         // q (f16)
  __shared__ __align__(16) _Float16 oh[2][4][BH];         // attention out (f16)
  __shared__ __align__(16) _Float16 xh[2][H_IN];          // input x (f16)
  __shared__ __align__(16) _Float16 genh[2][BH];          // gen row (f16)
  __shared__ float sc[2][NH][4][TT];
  __shared__ union Scr {
    float qkvp[3][2][4][BH];                              // QKV split-K partials (36KB)
    float wop[2][4][BH];                                  // Wo partials (12KB)
    struct { __align__(16) _Float16 f1h[2][4][4*BH];      // gelu out f16 (24KB)
             float w2p[2][4][BH]; } ffn;                  // W2 partials (12KB)
  } scr;
  __shared__ float redsum[4][12];
  __shared__ float redv[12];
  __shared__ int   redi[12];
  __shared__ int   amx[2];
  __shared__ int   fin[2];

  const int tid = threadIdx.x;
  const int kg  = tid / BH;        // split-K group (0/1); also seq index
  const int col = tid - kg * BH;   // 0..383
  const int sq  = kg;
  const int wid = tid >> 6;        // wave id 0..11
  const int seq0 = blockIdx.x * 2;

  if (tid < 2) fin[tid] = 0;

  // ---- stage x as f16 ----
  for (int s = 0; s < 2; s++) {
    const size_t base = (size_t)(seq0 + s) * H_IN;
    for (int j = tid; j < H_IN; j += NTH) xh[s][j] = (_Float16)x[base + j];
  }
  __syncthreads();
  // ---- x0 = (x_row @ Wproj).reshape(P, BH): thread owns cols {tid, tid+768} ----
  {
    float acc[2][2] = {};
    for (int j8 = 0; j8 < H_IN / 8; j8 += 4) {
      W16 w0[4], w1[4];
      #pragma unroll
      for (int u = 0; u < 4; u++) {
        w0[u].v8 = Wproj8[(size_t)(j8 + u) * (PP * BH) + tid];
        w1[u].v8 = Wproj8[(size_t)(j8 + u) * (PP * BH) + tid + NTH];
      }
      #pragma unroll
      for (int u = 0; u < 4; u++)
        #pragma unroll
        for (int s = 0; s < 2; s++) {
          W16 hv; hv.v8 = *(const h8*)&xh[s][(j8 + u) * 8];
          #pragma unroll
          for (int r = 0; r < 4; r++) {
            acc[s][0] = fdot2(hv.h[r], w0[u].h[r], acc[s][0]);
            acc[s][1] = fdot2(hv.h[r], w1[u].h[r], acc[s][1]);
          }
        }
    }
    const int m0 = tid / BH, cc = tid % BH;
    for (int s = 0; s < 2; s++) {
      xs[s][m0][cc]     = acc[s][0];
      xs[s][m0 + 2][cc] = acc[s][1];
    }
  }
  __syncthreads();

  auto layers = [&](auto ntc, int pos, bool causal) {
    constexpr int NT = decltype(ntc)::value;
    const int nk = pos + NT;
    for (int l = 0; l < NL; l++) {
      // ==== attn RMSNorm -> hh ====
      {
        #pragma unroll
        for (int tok = 0; tok < NT; tok++) {
          float r = xs[sq][tok][col]; r *= r;
          #pragma unroll
          for (int off = 32; off; off >>= 1) r += __shfl_down(r, off, 64);
          if ((tid & 63) == 0) redsum[tok][wid] = r;
        }
        __syncthreads();
        const int b = sq * 6;
        #pragma unroll
        for (int tok = 0; tok < NT; tok++) {
          float ss = redsum[tok][b] + redsum[tok][b+1] + redsum[tok][b+2] +
                     redsum[tok][b+3] + redsum[tok][b+4] + redsum[tok][b+5];
          float sca = rsqrtf(ss * (1.0f / BH) + 1e-5f);
          hh[sq][tok][col] = (_Float16)(xs[sq][tok][col] * sca * attn_norm[l * BH + col]);
        }
        __syncthreads();
      }
      // ==== q,k,v = h @ Wq/Wk/Wv (split-K; batched-issue U=4) ====
      {
        const size_t wb = ((size_t)l * 48 + kg * 24) * BH + col;
        float aq[2][NT] = {}, ak[2][NT] = {}, av[2][NT] = {};
        for (int j8 = 0; j8 < 24; j8 += 4) {
          W16 wq[4], wk[4], wv[4];
          #pragma unroll
          for (int u = 0; u < 4; u++) {
            wq[u].v8 = Wq8[wb + (size_t)(j8 + u) * BH];
            wk[u].v8 = Wk8[wb + (size_t)(j8 + u) * BH];
            wv[u].v8 = Wv8[wb + (size_t)(j8 + u) * BH];
          }
          #pragma unroll
          for (int u = 0; u < 4; u++)
            #pragma unroll
            for (int s = 0; s < 2; s++)
              #pragma unroll
              for (int tok = 0; tok < NT; tok++) {
                W16 hv; hv.v8 = *(const h8*)&hh[s][tok][(kg * 24 + j8 + u) * 8];
                #pragma unroll
                for (int r = 0; r < 4; r++) {
                  aq[s][tok] = fdot2(hv.h[r], wq[u].h[r], aq[s][tok]);
                  ak[s][tok] = fdot2(hv.h[r], wk[u].h[r], ak[s][tok]);
                  av[s][tok] = fdot2(hv.h[r], wv[u].h[r], av[s][tok]);
                }
              }
        }
        if (kg == 1) {
          #pragma unroll
          for (int s = 0; s < 2; s++)
            #pragma unroll
            for (int tok = 0; tok < NT; tok++) {
              scr.qkvp[0][s][tok][col] = aq[s][tok];
              scr.qkvp[1][s][tok][col] = ak[s][tok];
              scr.qkvp[2][s][tok][col] = av[s][tok];
            }
        }
        __syncthreads();
        if (kg == 0) {
          #pragma unroll
          for (int s = 0; s < 2; s++) {
            const size_t cb = (((size_t)(seq0 + s) * NL + l) * TT + pos) * BH + col;
            #pragma unroll
            for (int tok = 0; tok < NT; tok++) {
              qh[s][tok][col] = (_Float16)(aq[s][tok] + scr.qkvp[0][s][tok][col]);
              kbuf[cb + (size_t)tok * BH] = (_Float16)(ak[s][tok] + scr.qkvp[1][s][tok][col]);
              vbuf[cb + (size_t)tok * BH] = (_Float16)(av[s][tok] + scr.qkvp[2][s][tok][col]);
            }
          }
        }
        __syncthreads();
      }
      // ==== scores ====
      {
        const int nu = 2 * NH * NT * nk;   // <= 256
        if (tid < nu) {
          int s = tid / (NH * NT * nk), r = tid % (NH * NT * nk);
          int h = r / (NT * nk); int r2 = r % (NT * nk);
          int qi = r2 / nk, j = r2 % nk;
          float d;
          if (causal && j > pos + qi) d = -1e30f;
          else {
            const h8* kp8 = (const h8*)(kbuf + (((size_t)(seq0 + s) * NL + l) * TT + j) * BH + h * HD);
            W16 kk[6];
            #pragma unroll
            for (int c = 0; c < 6; c++) kk[c].v8 = kp8[c];
            d = 0.f;
            #pragma unroll
            for (int c = 0; c < 6; c++)
              #pragma unroll
              for (int e = 0; e < 8; e++)
                d += (float)qh[s][qi][h * HD + c * 8 + e] * (float)kk[c].e[e];
            d *= RSCALE;
          }
          sc[s][h][qi][j] = d;
        }
      }
      __syncthreads();
      // ==== softmax over keys ====
      {
        const int nr = 2 * NH * NT;
        if (tid < nr) {
          int s = tid / (NH * NT), r = tid % (NH * NT);
          int h = r / NT, qi = r % NT;
          float m = -3.0e38f;
          for (int j = 0; j < nk; j++) m = fmaxf(m, sc[s][h][qi][j]);
          float den = 0.f;
          for (int j = 0; j < nk; j++) {
            float e = expf(sc[s][h][qi][j] - m);
            sc[s][h][qi][j] = e; den += e;
          }
          float inv = 1.0f / den;
          for (int j = 0; j < nk; j++) sc[s][h][qi][j] *= inv;
        }
      }
      __syncthreads();
      // ==== o = p @ V  (batched 4-wide loads) ====
      {
        const size_t vb = (((size_t)(seq0 + sq) * NL + l) * TT) * BH + col;
        const int h = col / HD;
        #pragma unroll
        for (int tok = 0; tok < NT; tok++) {
          float acc = 0.f;
          int j = 0;
          for (; j + 4 <= nk; j += 4) {
            float v0 = (float)vbuf[vb + (size_t)(j + 0) * BH];
            float v1 = (float)vbuf[vb + (size_t)(j + 1) * BH];
            float v2 = (float)vbuf[vb + (size_t)(j + 2) * BH];
            float v3 = (float)vbuf[vb + (size_t)(j + 3) * BH];
            acc += sc[sq][h][tok][j] * v0 + sc[sq][h][tok][j+1] * v1 +
                   sc[sq][h][tok][j+2] * v2 + sc[sq][h][tok][j+3] * v3;
          }
          for (; j < nk; j++)
            acc += sc[sq][h][tok][j] * (float)vbuf[vb + (size_t)j * BH];
          oh[sq][tok][col] = (_Float16)acc;
        }
      }
      __syncthreads();
      // ==== x += o @ Wo (split-K; batched U=8) ====
      {
        const size_t wb = ((size_t)l * 48 + kg * 24) * BH + col;
        float ao[2][NT] = {};
        for (int j8 = 0; j8 < 24; j8 += 8) {
          W16 w[8];
          #pragma unroll
          for (int u = 0; u < 8; u++) w[u].v8 = Wo8[wb + (size_t)(j8 + u) * BH];
          #pragma unroll
          for (int u = 0; u < 8; u++)
            #pragma unroll
            for (int s = 0; s < 2; s++)
              #pragma unroll
              for (int tok = 0; tok < NT; tok++) {
                W16 hv; hv.v8 = *(const h8*)&oh[s][tok][(kg * 24 + j8 + u) * 8];
                #pragma unroll
                for (int r = 0; r < 4; r++)
                  ao[s][tok] = fdot2(hv.h[r], w[u].h[r], ao[s][tok]);
              }
        }
        if (kg == 1) {
          #pragma unroll
          for (int s = 0; s < 2; s++)
            #pragma unroll
            for (int tok = 0; tok < NT; tok++) scr.wop[s][tok][col] = ao[s][tok];
        }
        __syncthreads();
        if (kg == 0) {
          #pragma unroll
          for (int s = 0; s < 2; s++)
            #pragma unroll
            for (int tok = 0; tok < NT; tok++)
              xs[s][tok][col] += ao[s][tok] + scr.wop[s][tok][col];
        }
        __syncthreads();
      }
      // ==== ffn RMSNorm -> hh ====
      {
        #pragma unroll
        for (int tok = 0; tok < NT; tok++) {
          float r = xs[sq][tok][col]; r *= r;
          #pragma unroll
          for (int off = 32; off; off >>= 1) r += __shfl_down(r, off, 64);
          if ((tid & 63) == 0) redsum[tok][wid] = r;
        }
        __syncthreads();
        const int b = sq * 6;
        #pragma unroll
        for (int tok = 0; tok < NT; tok++) {
          float ss = redsum[tok][b] + redsum[tok][b+1] + redsum[tok][b+2] +
                     redsum[tok][b+3] + redsum[tok][b+4] + redsum[tok][b+5];
          float sca = rsqrtf(ss * (1.0f / BH) + 1e-5f);
          hh[sq][tok][col] = (_Float16)(xs[sq][tok][col] * sca * ffn_norm[l * BH + col]);
        }
        __syncthreads();
      }
      // ==== x += gelu(h @ W1) @ W2 — single pass over all NT tokens ====
      {
        // W1: thread owns cols {tid, tid+768}, full K; batched U=4 (8 loads)
        float a1[2][NT][2] = {};
        for (int j8 = 0; j8 < 48; j8 += 4) {
          W16 w0[4], w1[4];
          #pragma unroll
          for (int u = 0; u < 4; u++) {
            w0[u].v8 = W18[((size_t)(l * 48 + j8 + u)) * (4 * BH) + tid];
            w1[u].v8 = W18[((size_t)(l * 48 + j8 + u)) * (4 * BH) + tid + NTH];
          }
          #pragma unroll
          for (int u = 0; u < 4; u++)
            #pragma unroll
            for (int s = 0; s < 2; s++)
              #pragma unroll
              for (int t = 0; t < NT; t++) {
                W16 hv; hv.v8 = *(const h8*)&hh[s][t][(j8 + u) * 8];
                #pragma unroll
                for (int r = 0; r < 4; r++) {
                  a1[s][t][0] = fdot2(hv.h[r], w0[u].h[r], a1[s][t][0]);
                  a1[s][t][1] = fdot2(hv.h[r], w1[u].h[r], a1[s][t][1]);
                }
              }
        }
        #pragma unroll
        for (int s = 0; s < 2; s++)
          #pragma unroll
          for (int t = 0; t < NT; t++) {
            float z0 = a1[s][t][0], z1 = a1[s][t][1];
            scr.ffn.f1h[s][t][tid]       = (_Float16)(0.5f * z0 * (1.0f + erff(z0 * 0.7071067811865476f)));
            scr.ffn.f1h[s][t][tid + NTH] = (_Float16)(0.5f * z1 * (1.0f + erff(z1 * 0.7071067811865476f)));
          }
        __syncthreads();
        // W2: split-K (group kg owns rows [kg*768, kg*768+768)); batched U=8
        {
          float a2[2][NT] = {};
          for (int j8 = 0; j8 < 96; j8 += 8) {
            W16 w[8];
            #pragma unroll
            for (int u = 0; u < 8; u++)
              w[u].v8 = W28[((size_t)(l * 192 + kg * 96 + j8 + u)) * BH + col];
            #pragma unroll
            for (int u = 0; u < 8; u++)
              #pragma unroll
              for (int s = 0; s < 2; s++)
                #pragma unroll
                for (int t = 0; t < NT; t++) {
                  W16 fv; fv.v8 = *(const h8*)&scr.ffn.f1h[s][t][(kg * 96 + j8 + u) * 8];
                  #pragma unroll
                  for (int r = 0; r < 4; r++)
                    a2[s][t] = fdot2(fv.h[r], w[u].h[r], a2[s][t]);
                }
          }
          if (kg == 1) {
            #pragma unroll
            for (int s = 0; s < 2; s++)
              #pragma unroll
              for (int t = 0; t < NT; t++) scr.ffn.w2p[s][t][col] = a2[s][t];
          }
          __syncthreads();
          if (kg == 0) {
            #pragma unroll
            for (int s = 0; s < 2; s++)
              #pragma unroll
              for (int t = 0; t < NT; t++)
                xs[s][t][col] += a2[s][t] + scr.ffn.w2p[s][t][col];
          }
          __syncthreads();
        }
      }
    }
  };

  for (int i = 0; i < S_CNT; i++) {
    int grow;
    if (i == 0) { layers(IC<4>{}, 0, true);           grow = 3; }
    else        { layers(IC<1>{}, PP + i - 1, false); grow = 0; }

    // ---- argmax over hidden dims (both seqs in parallel; first-max tie-break) ----
    {
      float v = xs[sq][grow][col]; int idx = col;
      #pragma unroll
      for (int off = 32; off; off >>= 1) {
        float v2 = __shfl_down(v, off, 64); int i2 = __shfl_down(idx, off, 64);
        if (v2 > v || (v2 == v && i2 < idx)) { v = v2; idx = i2; }
      }
      if ((tid & 63) == 0) { redv[wid] = v; redi[wid] = idx; }
      __syncthreads();
      if (col == 0) {
        const int b = sq * 6;
        float bv = redv[b]; int bi = redi[b];
        for (int w = 1; w < 6; w++)
          if (redv[b + w] > bv || (redv[b + w] == bv && redi[b + w] < bi)) {
            bv = redv[b + w]; bi = redi[b + w];
          }
        amx[sq] = bi;
      }
      genh[sq][col] = (_Float16)xs[sq][grow][col];
      __syncthreads();
    }
    // ---- logits (zeroed if already finished) ----
    if (col < NV) {
      float acc = 0.f;
      for (int j8 = 0; j8 < 48; j8 += 8) {
        W16 w[8];
        #pragma unroll
        for (int u = 0; u < 8; u++) w[u].v8 = Wlm8[(size_t)(j8 + u) * NV + col];
        #pragma unroll
        for (int u = 0; u < 8; u++) {
          W16 gv; gv.v8 = *(const h8*)&genh[sq][(j8 + u) * 8];
          #pragma unroll
          for (int r = 0; r < 4; r++) acc = fdot2(gv.h[r], w[u].h[r], acc);
        }
      }
      out[((size_t)(seq0 + sq) * S_CNT + i) * NV + col] = fin[sq] ? 0.0f : acc;
    }
    __syncthreads();
    // ---- next token = (finished ? 0 : gen); then update finished ----
    {
      float gv = xs[sq][grow][col];
      xs[sq][0][col] = fin[sq] ? 0.0f : gv;
    }
    __syncthreads();
    if (tid < 2 && amx[tid] == EOS_I) fin[tid] = 1;
    __syncthreads();
  }
}

extern "C" void kernel_launch(void* const* d_in, const int* in_sizes, int n_in,
                              void* d_out, int out_size, void* d_ws, size_t ws_size,
                              hipStream_t stream) {
  const float* x     = (const float*)d_in[0];
  // d_in[1] = target (unused)
  const float* Wproj = (const float*)d_in[2];
  const float* an    = (const float*)d_in[3];
  const float* Wq    = (const float*)d_in[4];
  const float* Wk    = (const float*)d_in[5];
  const float* Wv    = (const float*)d_in[6];
  const float* Wo    = (const float*)d_in[7];
  const float* fn    = (const float*)d_in[8];
  const float* W1    = (const float*)d_in[9];
  const float* W2    = (const float*)d_in[10];
  const float* Wlm   = (const float*)d_in[11];
  float* out = (float*)d_out;
  (void)ws_size; (void)in_sizes; (void)n_in; (void)out_size;

  // ---- carve d_ws: h8-packed weights, then f16 KV ----
  h8* w = (h8*)d_ws;
  const int n_proj = (H_IN / 8) * (PP * BH);      // 196,608
  const int n_qkvo = NL * (BH / 8) * BH;          //  73,728 each
  const int n_w1   = NL * (BH / 8) * (4 * BH);    // 294,912
  const int n_w2   = NL * (4 * BH / 8) * BH;      // 294,912
  const int n_lm   = (BH / 8) * NV;               //  12,384
  h8* Wproj_p = w;  w += n_proj;
  h8* Wq_p    = w;  w += n_qkvo;
  h8* Wk_p    = w;  w += n_qkvo;
  h8* Wv_p    = w;  w += n_qkvo;
  h8* Wo_p    = w;  w += n_qkvo;
  h8* W1_p    = w;  w += n_w1;
  h8* W2_p    = w;  w += n_w2;
  h8* Wlm_p   = w;  w += n_lm;
  const size_t kv_elems = (size_t)NSEQ * NL * TT * BH;  // 12,582,912
  _Float16* kbuf = (_Float16*)w;
  _Float16* vbuf = kbuf + kv_elems;

  auto pack = [&](const float* src, h8* dst, int R, int C) {
    dim3 grid((C + 255) / 256, R / 8);
    pack8_kernel<<<grid, 256, 0, stream>>>(src, dst, C);
  };
  pack(Wproj, Wproj_p, H_IN,        PP * BH);
  pack(Wq,    Wq_p,    NL * BH,     BH);
  pack(Wk,    Wk_p,    NL * BH,     BH);
  pack(Wv,    Wv_p,    NL * BH,     BH);
  pack(Wo,    Wo_p,    NL * BH,     BH);
  pack(W1,    W1_p,    NL * BH,     4 * BH);
  pack(W2,    W2_p,    NL * 4 * BH, BH);
  pack(Wlm,   Wlm_p,   BH,          NV);

  decoder_kernel<<<NSEQ / 2, NTH, 0, stream>>>(
      x, Wproj_p, an, Wq_p, Wk_p, Wv_p, Wo_p, fn, W1_p, W2_p, Wlm_p, out, kbuf, vbuf);
}

// Round 8
// 2424.984 us; speedup vs baseline: 2.9237x; 1.0033x over previous
//
#include <hip/hip_runtime.h>
#include <hip/hip_bf16.h>

// ByteLevelDecoder: B=2,S=256,H=1024, BH=384,NH=8,HD=48, P=4,S_C=12,L=4,V=258,T=16
// Persistent kernel, 1 block = 2 sequences, 768 threads = 12 waves/CU.
// Round 8: RMSNorm gamma folded into packed weights (diag(g)W at pack time);
// x^2 reductions fused into GEMM epilogues (norm phases deleted); 1/sqrt(HD)
// folded into q; per-step tail collapsed 4 phases -> 2. Split-K for 384-col
// GEMMs; h8 weights (16B loads); f16 activations in LDS; KV f16 in d_ws.

constexpr int H_IN  = 1024;
constexpr int BH    = 384;
constexpr int NH    = 8;
constexpr int HD    = 48;
constexpr int PP    = 4;
constexpr int S_CNT = 12;
constexpr int NL    = 4;
constexpr int NV    = 258;
constexpr int TT    = 16;
constexpr int NSEQ  = 512;
constexpr int EOS_I = 257;
constexpr int NTH   = 768;
constexpr float RSCALE = 0.14433756729740646f;  // 1/sqrt(48)

typedef _Float16 h2 __attribute__((ext_vector_type(2)));
typedef _Float16 h8 __attribute__((ext_vector_type(8)));

union W16 { h8 v8; h2 h[4]; _Float16 e[8]; };

template<int N> struct IC { static constexpr int value = N; };

__device__ __forceinline__ float fdot2(h2 a, h2 b, float c) {
#if __has_builtin(__builtin_amdgcn_fdot2)
  return __builtin_amdgcn_fdot2(a, b, c, false);
#else
  return c + (float)a.x * (float)b.x + (float)a.y * (float)b.y;
#endif
}

// ---- repack prepass: dst[j8*C + c] = {g[8j8+r]*src[8*j8+r][c]}_{r=0..7} ----
__global__ __launch_bounds__(256)
void pack8_kernel(const float* __restrict__ src, const float* __restrict__ g,
                  h8* __restrict__ dst, int C) {
  int c  = blockIdx.x * 256 + threadIdx.x;
  int j8 = blockIdx.y;
  if (c < C) {
    h8 v;
    #pragma unroll
    for (int r = 0; r < 8; r++) {
      int row = 8 * j8 + r;
      float s = g ? g[row] : 1.0f;
      v[r] = (_Float16)(src[(size_t)row * C + c] * s);
    }
    dst[(size_t)j8 * C + c] = v;
  }
}

__global__ __launch_bounds__(NTH)
void decoder_kernel(const float* __restrict__ x,
                    const h8* __restrict__ Wproj8,   // [128][1536]
                    const h8* __restrict__ Wq8,      // [l*48][384], gamma-folded
                    const h8* __restrict__ Wk8,
                    const h8* __restrict__ Wv8,
                    const h8* __restrict__ Wo8,
                    const h8* __restrict__ W18,      // [l*48][1536], gamma-folded
                    const h8* __restrict__ W28,      // [l*192][384]
                    const h8* __restrict__ Wlm8,     // [48][258]
                    float* __restrict__ out,
                    _Float16* __restrict__ kbuf,
                    _Float16* __restrict__ vbuf)
{
  __shared__ float xs[2][4][BH];                     // residual stream (f32)
  __shared__ __align__(16) _Float16 xh[2][4][BH];    // residual as f16 (GEMM input)
  __shared__ __align__(16) _Float16 qh[2][4][BH];    // q (f16, pre-scaled)
  __shared__ __align__(16) _Float16 oh[2][4][BH];    // attention out (f16)
  __shared__ float sc[2][NH][4][TT];
  __shared__ __align__(16) union Scr {
    float qkvp[3][2][4][BH];                         // QKV split-K partials (36KB)
    float wop[2][4][BH];                             // Wo partials (12KB)
    struct { __align__(16) _Float16 f1h[2][4][4*BH]; // gelu out f16 (24KB)
             float w2p[2][4][BH]; } ffn;             // W2 partials (12KB)
    __align__(16) _Float16 xin[2][H_IN];             // staged input x (4KB)
  } scr;
  __shared__ float redsq[2][4][6];                   // x^2 wave-sums per (s,tok)
  __shared__ float redv[12];
  __shared__ int   redi[12];
  __shared__ int   fin[2];

  const int tid = threadIdx.x;
  const int kg  = tid / BH;        // split-K group (0/1); also seq index
  const int col = tid - kg * BH;   // 0..383
  const int sq  = kg;
  const int wid = tid >> 6;        // wave id 0..11
  const int w6  = wid % 6;
  const int seq0 = blockIdx.x * 2;

  if (tid < 2) fin[tid] = 0;

  // ---- stage x as f16 ----
  for (int s = 0; s < 2; s++) {
    const size_t base = (size_t)(seq0 + s) * H_IN;
    for (int j = tid; j < H_IN; j += NTH) scr.xin[s][j] = (_Float16)x[base + j];
  }
  __syncthreads();
  // ---- x0 = (x_row @ Wproj).reshape(P, BH); epilogue fuses f16 stage + x^2 sums ----
  {
    float acc[2][2] = {};
    for (int j8 = 0; j8 < H_IN / 8; j8 += 4) {
      W16 w0[4], w1[4];
      #pragma unroll
      for (int u = 0; u < 4; u++) {
        w0[u].v8 = Wproj8[(size_t)(j8 + u) * (PP * BH) + tid];
        w1[u].v8 = Wproj8[(size_t)(j8 + u) * (PP * BH) + tid + NTH];
      }
      #pragma unroll
      for (int u = 0; u < 4; u++)
        #pragma unroll
        for (int s = 0; s < 2; s++) {
          W16 hv; hv.v8 = *(const h8*)&scr.xin[s][(j8 + u) * 8];
          #pragma unroll
          for (int r = 0; r < 4; r++) {
            acc[s][0] = fdot2(hv.h[r], w0[u].h[r], acc[s][0]);
            acc[s][1] = fdot2(hv.h[r], w1[u].h[r], acc[s][1]);
          }
        }
    }
    const int m0 = tid / BH, cc = tid - m0 * BH;     // tok pair (m0, m0+2)
    #pragma unroll
    for (int s = 0; s < 2; s++) {
      xs[s][m0][cc]     = acc[s][0];  xh[s][m0][cc]     = (_Float16)acc[s][0];
      xs[s][m0 + 2][cc] = acc[s][1];  xh[s][m0 + 2][cc] = (_Float16)acc[s][1];
      float r0 = acc[s][0] * acc[s][0], r1 = acc[s][1] * acc[s][1];
      #pragma unroll
      for (int off = 32; off; off >>= 1) {
        r0 += __shfl_down(r0, off, 64); r1 += __shfl_down(r1, off, 64);
      }
      if ((tid & 63) == 0) { redsq[s][m0][w6] = r0; redsq[s][m0 + 2][w6] = r1; }
    }
  }
  __syncthreads();

  auto layers = [&](auto ntc, int pos, bool causal) {
    constexpr int NT = decltype(ntc)::value;
    const int nk = pos + NT;
    for (int l = 0; l < NL; l++) {
      // ==== q,k,v = sca * (x @ gW) (split-K; gamma folded; sca at epilogue) ====
      {
        const size_t wb = ((size_t)l * 48 + kg * 24) * BH + col;
        float aq[2][NT] = {}, ak[2][NT] = {}, av[2][NT] = {};
        for (int j8 = 0; j8 < 24; j8 += 4) {
          W16 wq[4], wk[4], wv[4];
          #pragma unroll
          for (int u = 0; u < 4; u++) {
            wq[u].v8 = Wq8[wb + (size_t)(j8 + u) * BH];
            wk[u].v8 = Wk8[wb + (size_t)(j8 + u) * BH];
            wv[u].v8 = Wv8[wb + (size_t)(j8 + u) * BH];
          }
          #pragma unroll
          for (int u = 0; u < 4; u++)
            #pragma unroll
            for (int s = 0; s < 2; s++)
              #pragma unroll
              for (int tok = 0; tok < NT; tok++) {
                W16 hv; hv.v8 = *(const h8*)&xh[s][tok][(kg * 24 + j8 + u) * 8];
                #pragma unroll
                for (int r = 0; r < 4; r++) {
                  aq[s][tok] = fdot2(hv.h[r], wq[u].h[r], aq[s][tok]);
                  ak[s][tok] = fdot2(hv.h[r], wk[u].h[r], ak[s][tok]);
                  av[s][tok] = fdot2(hv.h[r], wv[u].h[r], av[s][tok]);
                }
              }
        }
        if (kg == 1) {
          #pragma unroll
          for (int s = 0; s < 2; s++)
            #pragma unroll
            for (int tok = 0; tok < NT; tok++) {
              scr.qkvp[0][s][tok][col] = aq[s][tok];
              scr.qkvp[1][s][tok][col] = ak[s][tok];
              scr.qkvp[2][s][tok][col] = av[s][tok];
            }
        }
        __syncthreads();
        if (kg == 0) {
          #pragma unroll
          for (int s = 0; s < 2; s++) {
            const size_t cb = (((size_t)(seq0 + s) * NL + l) * TT + pos) * BH + col;
            #pragma unroll
            for (int tok = 0; tok < NT; tok++) {
              float ss = redsq[s][tok][0] + redsq[s][tok][1] + redsq[s][tok][2] +
                         redsq[s][tok][3] + redsq[s][tok][4] + redsq[s][tok][5];
              float sca = rsqrtf(ss * (1.0f / BH) + 1e-5f);
              qh[s][tok][col] = (_Float16)((aq[s][tok] + scr.qkvp[0][s][tok][col]) * sca * RSCALE);
              kbuf[cb + (size_t)tok * BH] = (_Float16)((ak[s][tok] + scr.qkvp[1][s][tok][col]) * sca);
              vbuf[cb + (size_t)tok * BH] = (_Float16)((av[s][tok] + scr.qkvp[2][s][tok][col]) * sca);
            }
          }
        }
        __syncthreads();
      }
      // ==== scores (RSCALE pre-folded into q) ====
      {
        const int nu = 2 * NH * NT * nk;   // <= 256
        if (tid < nu) {
          int s = tid / (NH * NT * nk), r = tid % (NH * NT * nk);
          int h = r / (NT * nk); int r2 = r % (NT * nk);
          int qi = r2 / nk, j = r2 % nk;
          float d;
          if (causal && j > pos + qi) d = -1e30f;
          else {
            const h8* kp8 = (const h8*)(kbuf + (((size_t)(seq0 + s) * NL + l) * TT + j) * BH + h * HD);
            W16 kk[6];
            #pragma unroll
            for (int c = 0; c < 6; c++) kk[c].v8 = kp8[c];
            d = 0.f;
            #pragma unroll
            for (int c = 0; c < 6; c++)
              #pragma unroll
              for (int e = 0; e < 8; e++)
                d += (float)qh[s][qi][h * HD + c * 8 + e] * (float)kk[c].e[e];
          }
          sc[s][h][qi][j] = d;
        }
      }
      __syncthreads();
      // ==== softmax over keys ====
      {
        const int nr = 2 * NH * NT;
        if (tid < nr) {
          int s = tid / (NH * NT), r = tid % (NH * NT);
          int h = r / NT, qi = r % NT;
          float m = -3.0e38f;
          for (int j = 0; j < nk; j++) m = fmaxf(m, sc[s][h][qi][j]);
          float den = 0.f;
          for (int j = 0; j < nk; j++) {
            float e = expf(sc[s][h][qi][j] - m);
            sc[s][h][qi][j] = e; den += e;
          }
          float inv = 1.0f / den;
          for (int j = 0; j < nk; j++) sc[s][h][qi][j] *= inv;
        }
      }
      __syncthreads();
      // ==== o = p @ V ====
      {
        const size_t vb = (((size_t)(seq0 + sq) * NL + l) * TT) * BH + col;
        const int h = col / HD;
        #pragma unroll
        for (int tok = 0; tok < NT; tok++) {
          float acc = 0.f;
          int j = 0;
          for (; j + 4 <= nk; j += 4) {
            float v0 = (float)vbuf[vb + (size_t)(j + 0) * BH];
            float v1 = (float)vbuf[vb + (size_t)(j + 1) * BH];
            float v2 = (float)vbuf[vb + (size_t)(j + 2) * BH];
            float v3 = (float)vbuf[vb + (size_t)(j + 3) * BH];
            acc += sc[sq][h][tok][j] * v0 + sc[sq][h][tok][j+1] * v1 +
                   sc[sq][h][tok][j+2] * v2 + sc[sq][h][tok][j+3] * v3;
          }
          for (; j < nk; j++)
            acc += sc[sq][h][tok][j] * (float)vbuf[vb + (size_t)j * BH];
          oh[sq][tok][col] = (_Float16)acc;
        }
      }
      __syncthreads();
      // ==== x += o @ Wo (split-K); epilogue fuses xh stage + x^2 sums ====
      {
        const size_t wb = ((size_t)l * 48 + kg * 24) * BH + col;
        float ao[2][NT] = {};
        for (int j8 = 0; j8 < 24; j8 += 8) {
          W16 w[8];
          #pragma unroll
          for (int u = 0; u < 8; u++) w[u].v8 = Wo8[wb + (size_t)(j8 + u) * BH];
          #pragma unroll
          for (int u = 0; u < 8; u++)
            #pragma unroll
            for (int s = 0; s < 2; s++)
              #pragma unroll
              for (int tok = 0; tok < NT; tok++) {
                W16 hv; hv.v8 = *(const h8*)&oh[s][tok][(kg * 24 + j8 + u) * 8];
                #pragma unroll
                for (int r = 0; r < 4; r++)
                  ao[s][tok] = fdot2(hv.h[r], w[u].h[r], ao[s][tok]);
              }
        }
        if (kg == 1) {
          #pragma unroll
          for (int s = 0; s < 2; s++)
            #pragma unroll
            for (int tok = 0; tok < NT; tok++) scr.wop[s][tok][col] = ao[s][tok];
        }
        __syncthreads();
        if (kg == 0) {
          #pragma unroll
          for (int s = 0; s < 2; s++)
            #pragma unroll
            for (int tok = 0; tok < NT; tok++) {
              float xn = xs[s][tok][col] + ao[s][tok] + scr.wop[s][tok][col];
              xs[s][tok][col] = xn; xh[s][tok][col] = (_Float16)xn;
              float r = xn * xn;
              #pragma unroll
              for (int off = 32; off; off >>= 1) r += __shfl_down(r, off, 64);
              if ((tid & 63) == 0) redsq[s][tok][wid] = r;
            }
        }
        __syncthreads();
      }
      // ==== x += gelu(sca2 * (x @ gW1)) @ W2 (gamma folded; sca2 at gelu) ====
      {
        float a1[2][NT][2] = {};
        for (int j8 = 0; j8 < 48; j8 += 4) {
          W16 w0[4], w1[4];
          #pragma unroll
          for (int u = 0; u < 4; u++) {
            w0[u].v8 = W18[((size_t)(l * 48 + j8 + u)) * (4 * BH) + tid];
            w1[u].v8 = W18[((size_t)(l * 48 + j8 + u)) * (4 * BH) + tid + NTH];
          }
          #pragma unroll
          for (int u = 0; u < 4; u++)
            #pragma unroll
            for (int s = 0; s < 2; s++)
              #pragma unroll
              for (int t = 0; t < NT; t++) {
                W16 hv; hv.v8 = *(const h8*)&xh[s][t][(j8 + u) * 8];
                #pragma unroll
                for (int r = 0; r < 4; r++) {
                  a1[s][t][0] = fdot2(hv.h[r], w0[u].h[r], a1[s][t][0]);
                  a1[s][t][1] = fdot2(hv.h[r], w1[u].h[r], a1[s][t][1]);
                }
              }
        }
        #pragma unroll
        for (int s = 0; s < 2; s++)
          #pragma unroll
          for (int t = 0; t < NT; t++) {
            float ss = redsq[s][t][0] + redsq[s][t][1] + redsq[s][t][2] +
                       redsq[s][t][3] + redsq[s][t][4] + redsq[s][t][5];
            float sca = rsqrtf(ss * (1.0f / BH) + 1e-5f);
            float z0 = a1[s][t][0] * sca, z1 = a1[s][t][1] * sca;
            scr.ffn.f1h[s][t][tid]       = (_Float16)(0.5f * z0 * (1.0f + erff(z0 * 0.7071067811865476f)));
            scr.ffn.f1h[s][t][tid + NTH] = (_Float16)(0.5f * z1 * (1.0f + erff(z1 * 0.7071067811865476f)));
          }
        __syncthreads();
        // W2: split-K; epilogue fuses xh stage + x^2 sums (for next layer's QKV)
        {
          float a2[2][NT] = {};
          for (int j8 = 0; j8 < 96; j8 += 8) {
            W16 w[8];
            #pragma unroll
            for (int u = 0; u < 8; u++)
              w[u].v8 = W28[((size_t)(l * 192 + kg * 96 + j8 + u)) * BH + col];
            #pragma unroll
            for (int u = 0; u < 8; u++)
              #pragma unroll
              for (int s = 0; s < 2; s++)
                #pragma unroll
                for (int t = 0; t < NT; t++) {
                  W16 fv; fv.v8 = *(const h8*)&scr.ffn.f1h[s][t][(kg * 96 + j8 + u) * 8];
                  #pragma unroll
                  for (int r = 0; r < 4; r++)
                    a2[s][t] = fdot2(fv.h[r], w[u].h[r], a2[s][t]);
                }
          }
          if (kg == 1) {
            #pragma unroll
            for (int s = 0; s < 2; s++)
              #pragma unroll
              for (int t = 0; t < NT; t++) scr.ffn.w2p[s][t][col] = a2[s][t];
          }
          __syncthreads();
          if (kg == 0) {
            #pragma unroll
            for (int s = 0; s < 2; s++)
              #pragma unroll
              for (int t = 0; t < NT; t++) {
                float xn = xs[s][t][col] + a2[s][t] + scr.ffn.w2p[s][t][col];
                xs[s][t][col] = xn; xh[s][t][col] = (_Float16)xn;
                float r = xn * xn;
                #pragma unroll
                for (int off = 32; off; off >>= 1) r += __shfl_down(r, off, 64);
                if ((tid & 63) == 0) redsq[s][t][wid] = r;
              }
          }
          __syncthreads();
        }
      }
    }
  };

  for (int i = 0; i < S_CNT; i++) {
    int grow;
    if (i == 0) { layers(IC<4>{}, 0, true);           grow = 3; }
    else        { layers(IC<1>{}, PP + i - 1, false); grow = 0; }

    // ---- phase A: argmax partials + next-token copy (fused f16 stage + sums) ----
    {
      float gen = xs[sq][grow][col];
      float v = gen; int idx = col;
      #pragma unroll
      for (int off = 32; off; off >>= 1) {
        float v2 = __shfl_down(v, off, 64); int i2 = __shfl_down(idx, off, 64);
        if (v2 > v || (v2 == v && i2 < idx)) { v = v2; idx = i2; }
      }
      if ((tid & 63) == 0) { redv[wid] = v; redi[wid] = idx; }
      float nxt = fin[sq] ? 0.0f : gen;
      xs[sq][0][col] = nxt; xh[sq][0][col] = (_Float16)nxt;
      float r = nxt * nxt;
      #pragma unroll
      for (int off = 32; off; off >>= 1) r += __shfl_down(r, off, 64);
      if ((tid & 63) == 0) redsq[sq][0][w6] = r;
      __syncthreads();
    }
    // ---- phase B: argmax finalize (+fin update by same thread) + fin-free logits ----
    {
      if (col == 0) {
        const int b = sq * 6;
        float bv = redv[b]; int bi = redi[b];
        for (int w = 1; w < 6; w++)
          if (redv[b + w] > bv || (redv[b + w] == bv && redi[b + w] < bi)) {
            bv = redv[b + w]; bi = redi[b + w];
          }
        if (bi == EOS_I) fin[sq] = 1;
      }
      if (col < NV) {
        float acc = 0.f;
        for (int j8 = 0; j8 < 48; j8 += 8) {
          W16 w[8];
          #pragma unroll
          for (int u = 0; u < 8; u++) w[u].v8 = Wlm8[(size_t)(j8 + u) * NV + col];
          #pragma unroll
          for (int u = 0; u < 8; u++) {
            W16 gv; gv.v8 = *(const h8*)&xh[sq][0][(j8 + u) * 8];
            #pragma unroll
            for (int r = 0; r < 4; r++) acc = fdot2(gv.h[r], w[u].h[r], acc);
          }
        }
        out[((size_t)(seq0 + sq) * S_CNT + i) * NV + col] = acc;
      }
      __syncthreads();
    }
  }
}

extern "C" void kernel_launch(void* const* d_in, const int* in_sizes, int n_in,
                              void* d_out, int out_size, void* d_ws, size_t ws_size,
                              hipStream_t stream) {
  const float* x     = (const float*)d_in[0];
  // d_in[1] = target (unused)
  const float* Wproj = (const float*)d_in[2];
  const float* an    = (const float*)d_in[3];
  const float* Wq    = (const float*)d_in[4];
  const float* Wk    = (const float*)d_in[5];
  const float* Wv    = (const float*)d_in[6];
  const float* Wo    = (const float*)d_in[7];
  const float* fn    = (const float*)d_in[8];
  const float* W1    = (const float*)d_in[9];
  const float* W2    = (const float*)d_in[10];
  const float* Wlm   = (const float*)d_in[11];
  float* out = (float*)d_out;
  (void)ws_size; (void)in_sizes; (void)n_in; (void)out_size;

  // ---- carve d_ws: h8-packed weights (gamma folded into Wq/Wk/Wv/W1), then f16 KV ----
  h8* w = (h8*)d_ws;
  const int n_proj = (H_IN / 8) * (PP * BH);
  const int n_qkvo = NL * (BH / 8) * BH;
  const int n_w1   = NL * (BH / 8) * (4 * BH);
  const int n_w2   = NL * (4 * BH / 8) * BH;
  const int n_lm   = (BH / 8) * NV;
  h8* Wproj_p = w;  w += n_proj;
  h8* Wq_p    = w;  w += n_qkvo;
  h8* Wk_p    = w;  w += n_qkvo;
  h8* Wv_p    = w;  w += n_qkvo;
  h8* Wo_p    = w;  w += n_qkvo;
  h8* W1_p    = w;  w += n_w1;
  h8* W2_p    = w;  w += n_w2;
  h8* Wlm_p   = w;  w += n_lm;
  const size_t kv_elems = (size_t)NSEQ * NL * TT * BH;
  _Float16* kbuf = (_Float16*)w;
  _Float16* vbuf = kbuf + kv_elems;

  auto pack = [&](const float* src, const float* g, h8* dst, int R, int C) {
    dim3 grid((C + 255) / 256, R / 8);
    pack8_kernel<<<grid, 256, 0, stream>>>(src, g, dst, C);
  };
  pack(Wproj, nullptr, Wproj_p, H_IN,        PP * BH);
  pack(Wq,    an,      Wq_p,    NL * BH,     BH);
  pack(Wk,    an,      Wk_p,    NL * BH,     BH);
  pack(Wv,    an,      Wv_p,    NL * BH,     BH);
  pack(Wo,    nullptr, Wo_p,    NL * BH,     BH);
  pack(W1,    fn,      W1_p,    NL * BH,     4 * BH);
  pack(W2,    nullptr, W2_p,    NL * 4 * BH, BH);
  pack(Wlm,   nullptr, Wlm_p,   BH,          NV);

  decoder_kernel<<<NSEQ / 2, NTH, 0, stream>>>(
      x, Wproj_p, Wq_p, Wk_p, Wv_p, Wo_p, W1_p, W2_p, Wlm_p, out, kbuf, vbuf);
}